// Round 1
// baseline (283.296 us; speedup 1.0000x reference)
//
#include <hip/hip_runtime.h>

#define HH 64
#define WW 64
#define DD 256
#define NB 2
#define NCH 96   // 64 offset channels + 32 attn channels

// ---------------------------------------------------------------------------
// K0: repack weights: wt2[tap][cc][ci4][ch][e]  (ci = cc*64 + ci4*4 + e)
// so the conv kernel can stage float4-contiguous, coalesced weight tiles.
// ---------------------------------------------------------------------------
__global__ __launch_bounds__(256) void wt_kernel(const float* __restrict__ ow,
                                                 const float* __restrict__ aw,
                                                 float* __restrict__ wt2) {
    int o = blockIdx.x * 256 + threadIdx.x;
    if (o >= 9 * 4 * 16 * 96 * 4) return;
    int e = o & 3;
    int t = o >> 2;
    int ch = t % 96;  t /= 96;
    int ci4 = t & 15; t >>= 4;
    int cc = t & 3;   t >>= 2;
    int tap = t;                       // 0..8  (ky*3+kx)
    int ci = cc * 64 + ci4 * 4 + e;
    float v = (ch < 64) ? ow[(ch * 256 + ci) * 9 + tap]
                        : aw[((ch - 64) * 256 + ci) * 9 + tap];
    wt2[o] = v;
}

// ---------------------------------------------------------------------------
// K1: 3x3 conv, SAME zero-pad, input x is channels-last (B, H*W, D).
// Block: 32 pixels (half row) x all 96 out channels. 256 threads.
// Thread tile: 3 channels x 4 pixels. ci chunked by 64 (4 chunks).
// conv output layout: [b][ch][y][x] fp32.
// ---------------------------------------------------------------------------
__global__ __launch_bounds__(256) void conv_kernel(const float* __restrict__ x,
                                                   const float* __restrict__ wt2,
                                                   const float* __restrict__ offb,
                                                   const float* __restrict__ attb,
                                                   float* __restrict__ conv) {
    __shared__ float4 lx[3][16][34];   // [row][ci4][col]; col = gx - (x0-1)
    __shared__ float4 lw[16][96];      // [ci4][ch], float4 over ci
    int blk = blockIdx.x;
    int xh = blk & 1, y = (blk >> 1) & 63, b = blk >> 7;
    int x0 = xh * 32;
    int tid = threadIdx.x;
    int chg = tid >> 3;                // 0..31 -> channels {chg, chg+32, chg+64}
    int pxg = tid & 7;                 // 0..7  -> pixels  {pxg + 8*p}
    float acc[3][4];
#pragma unroll
    for (int c = 0; c < 3; ++c)
#pragma unroll
        for (int p = 0; p < 4; ++p) acc[c][p] = 0.f;

    for (int cc = 0; cc < 4; ++cc) {
        __syncthreads();               // prior reads of lx done
        for (int idx = tid; idx < 3 * 34 * 16; idx += 256) {
            int ci4 = idx & 15;
            int col = (idx >> 4) % 34;
            int r = idx / (16 * 34);
            int gy = y + r - 1, gx = x0 + col - 1;
            float4 v = make_float4(0.f, 0.f, 0.f, 0.f);
            if (gy >= 0 && gy < HH && gx >= 0 && gx < WW)
                v = *reinterpret_cast<const float4*>(
                    &x[(size_t)((b * HH * WW) + gy * WW + gx) * DD + cc * 64 + ci4 * 4]);
            lx[r][ci4][col] = v;
        }
        for (int tap = 0; tap < 9; ++tap) {
            __syncthreads();           // lx staged / prior lw reads done
            const float4* wsrc =
                reinterpret_cast<const float4*>(wt2) + (tap * 4 + cc) * (16 * 96);
            float4* lwf = &lw[0][0];
            for (int idx = tid; idx < 16 * 96; idx += 256) lwf[idx] = wsrc[idx];
            __syncthreads();
            int ky = tap / 3, kx = tap % 3;
#pragma unroll 4
            for (int ci4 = 0; ci4 < 16; ++ci4) {
                float4 w0 = lw[ci4][chg];
                float4 w1 = lw[ci4][chg + 32];
                float4 w2 = lw[ci4][chg + 64];
#pragma unroll
                for (int p = 0; p < 4; ++p) {
                    float4 xv = lx[ky][ci4][pxg + 8 * p + kx];
                    acc[0][p] = fmaf(w0.x, xv.x, acc[0][p]);
                    acc[0][p] = fmaf(w0.y, xv.y, acc[0][p]);
                    acc[0][p] = fmaf(w0.z, xv.z, acc[0][p]);
                    acc[0][p] = fmaf(w0.w, xv.w, acc[0][p]);
                    acc[1][p] = fmaf(w1.x, xv.x, acc[1][p]);
                    acc[1][p] = fmaf(w1.y, xv.y, acc[1][p]);
                    acc[1][p] = fmaf(w1.z, xv.z, acc[1][p]);
                    acc[1][p] = fmaf(w1.w, xv.w, acc[1][p]);
                    acc[2][p] = fmaf(w2.x, xv.x, acc[2][p]);
                    acc[2][p] = fmaf(w2.y, xv.y, acc[2][p]);
                    acc[2][p] = fmaf(w2.z, xv.z, acc[2][p]);
                    acc[2][p] = fmaf(w2.w, xv.w, acc[2][p]);
                }
            }
        }
    }
#pragma unroll
    for (int c = 0; c < 3; ++c) {
        int ch = chg + 32 * c;
        float bias = (ch < 64) ? offb[ch] : attb[ch - 64];
#pragma unroll
        for (int p = 0; p < 4; ++p) {
            int px = pxg + 8 * p;
            conv[(size_t)((b * NCH + ch) * HH + y) * WW + x0 + px] = acc[c][p] + bias;
        }
    }
}

// ---------------------------------------------------------------------------
// K2: softmax over p + bilinear sampling + weighted sum + head-mean.
// One wave per query. Output S[b*4096 + i*64 + j][d]:
//   S = (1/8) sum_{h,p} attn[b,h,p, y=i, x=j] * sample(b,h,p,d; y=j, x=i)
// (the transposed attn/sample pairing is intentional — it matches the ref).
// ---------------------------------------------------------------------------
__global__ __launch_bounds__(256) void sample_kernel(const float* __restrict__ x,
                                                     const float* __restrict__ conv,
                                                     float* __restrict__ S) {
    __shared__ float s_coef[4][32][4];
    __shared__ int s_pix[4][32][4];
    int tid = threadIdx.x;
    int wid = tid >> 6, lane = tid & 63;
    int q = blockIdx.x * 4 + wid;            // 0..8191
    int b = q >> 12, qi = (q >> 6) & 63, qj = q & 63;
    const float* convb = conv + (size_t)b * (NCH * HH * WW);

    if (lane < 32) {
        int s = lane;                        // sample index: head = s>>2, p = s&3
        // attention logit at spatial (y=qi, x=qj)
        float logit = convb[(64 + s) * 4096 + qi * 64 + qj];
        float m = logit;
        m = fmaxf(m, __shfl_xor(m, 1));
        m = fmaxf(m, __shfl_xor(m, 2));
        float e = __expf(logit - m);
        float sum = e;
        sum += __shfl_xor(sum, 1);
        sum += __shfl_xor(sum, 2);
        float a = e / sum * 0.125f;          // softmax over p, folded head-mean

        // offsets at spatial (y=qj, x=qi)
        float ox = convb[(2 * s) * 4096 + qj * 64 + qi];
        float oy = convb[(2 * s + 1) * 4096 + qj * 64 + qi];
        float gx = (float)qi * (1.f / 63.f) + 0.1f * ox;
        float gy = (float)qj * (1.f / 63.f) + 0.1f * oy;
        float ix = ((gx + 1.f) * 64.f - 1.f) * 0.5f;
        float iy = ((gy + 1.f) * 64.f - 1.f) * 0.5f;
        float x0f = floorf(ix), y0f = floorf(iy);
        float wx = ix - x0f, wy = iy - y0f;
        int x0 = (int)x0f, y0 = (int)y0f;
#pragma unroll
        for (int c = 0; c < 4; ++c) {
            int xi = x0 + (c & 1), yi = y0 + (c >> 1);
            float w = ((c & 1) ? wx : 1.f - wx) * ((c >> 1) ? wy : 1.f - wy);
            bool valid = (xi >= 0) && (xi < 64) && (yi >= 0) && (yi < 64);
            int xc = min(max(xi, 0), 63), yc = min(max(yi, 0), 63);
            s_coef[wid][s][c] = valid ? a * w : 0.f;
            s_pix[wid][s][c] = yc * 64 + xc;
        }
    }
    __syncthreads();

    const float4* xb = reinterpret_cast<const float4*>(x) + (size_t)b * 4096 * 64;
    float4 acc = make_float4(0.f, 0.f, 0.f, 0.f);
    for (int s = 0; s < 32; ++s) {
        float4 cf = *reinterpret_cast<const float4*>(&s_coef[wid][s][0]);
        int4 pp = *reinterpret_cast<const int4*>(&s_pix[wid][s][0]);
        float cfa[4] = {cf.x, cf.y, cf.z, cf.w};
        int ppa[4] = {pp.x, pp.y, pp.z, pp.w};
#pragma unroll
        for (int c = 0; c < 4; ++c) {
            float coef = cfa[c];
            if (coef != 0.f) {               // wave-uniform branch
                float4 v = xb[(size_t)ppa[c] * 64 + lane];
                acc.x = fmaf(coef, v.x, acc.x);
                acc.y = fmaf(coef, v.y, acc.y);
                acc.z = fmaf(coef, v.z, acc.z);
                acc.w = fmaf(coef, v.w, acc.w);
            }
        }
    }
    reinterpret_cast<float4*>(S)[(size_t)q * 64 + lane] = acc;
}

// ---------------------------------------------------------------------------
// K3: out[m][n] = sum_k S[m][k] * out_w[n][k] + out_b[n]
// M=8192, N=256, K=256. 64x64 tile, 4x4 per thread.
// ---------------------------------------------------------------------------
__global__ __launch_bounds__(256) void gemm_kernel(const float* __restrict__ S,
                                                   const float* __restrict__ wO,
                                                   const float* __restrict__ bO,
                                                   float* __restrict__ out) {
    __shared__ float la[16][68];
    __shared__ float lb[16][68];
    int tid = threadIdx.x;
    int bm = blockIdx.x, bn = blockIdx.y;
    int tm = tid >> 4, tn = tid & 15;
    int lr = tid >> 2, lk = (tid & 3) * 4;
    float acc[4][4];
#pragma unroll
    for (int i = 0; i < 4; ++i)
#pragma unroll
        for (int j = 0; j < 4; ++j) acc[i][j] = 0.f;

    for (int kc = 0; kc < 256; kc += 16) {
        __syncthreads();
        float4 va = *reinterpret_cast<const float4*>(
            &S[(size_t)(bm * 64 + lr) * 256 + kc + lk]);
        la[lk + 0][lr] = va.x; la[lk + 1][lr] = va.y;
        la[lk + 2][lr] = va.z; la[lk + 3][lr] = va.w;
        float4 vb = *reinterpret_cast<const float4*>(
            &wO[(size_t)(bn * 64 + lr) * 256 + kc + lk]);
        lb[lk + 0][lr] = vb.x; lb[lk + 1][lr] = vb.y;
        lb[lk + 2][lr] = vb.z; lb[lk + 3][lr] = vb.w;
        __syncthreads();
#pragma unroll
        for (int k = 0; k < 16; ++k) {
            float4 av = *reinterpret_cast<const float4*>(&la[k][tm * 4]);
            float4 bv = *reinterpret_cast<const float4*>(&lb[k][tn * 4]);
            float a4[4] = {av.x, av.y, av.z, av.w};
            float b4[4] = {bv.x, bv.y, bv.z, bv.w};
#pragma unroll
            for (int i = 0; i < 4; ++i)
#pragma unroll
                for (int j = 0; j < 4; ++j)
                    acc[i][j] = fmaf(a4[i], b4[j], acc[i][j]);
        }
    }
#pragma unroll
    for (int i = 0; i < 4; ++i) {
        int m = bm * 64 + tm * 4 + i;
#pragma unroll
        for (int j = 0; j < 4; ++j) {
            int n = bn * 64 + tn * 4 + j;
            out[(size_t)m * 256 + n] = acc[i][j] + bO[n];
        }
    }
}

extern "C" void kernel_launch(void* const* d_in, const int* in_sizes, int n_in,
                              void* d_out, int out_size, void* d_ws, size_t ws_size,
                              hipStream_t stream) {
    const float* x  = (const float*)d_in[0];
    const float* ow = (const float*)d_in[1];
    const float* ob = (const float*)d_in[2];
    const float* aw = (const float*)d_in[3];
    const float* ab = (const float*)d_in[4];
    const float* wO = (const float*)d_in[5];
    const float* bO = (const float*)d_in[6];
    float* out = (float*)d_out;

    char* ws = (char*)d_ws;
    float* wt2  = (float*)(ws);                          // 221184 f = 884736 B
    float* conv = (float*)(ws + 884736);                 // 786432 f = 3145728 B
    float* S    = (float*)(ws + 884736 + 3145728);       // 2097152 f = 8388608 B

    hipLaunchKernelGGL(wt_kernel, dim3(864), dim3(256), 0, stream, ow, aw, wt2);
    hipLaunchKernelGGL(conv_kernel, dim3(NB * HH * 2), dim3(256), 0, stream,
                       x, wt2, ob, ab, conv);
    hipLaunchKernelGGL(sample_kernel, dim3(2048), dim3(256), 0, stream, x, conv, S);
    hipLaunchKernelGGL(gemm_kernel, dim3(128, 4), dim3(256), 0, stream, S, wO, bO, out);
}

// Round 2
// 131.957 us; speedup vs baseline: 2.1469x; 2.1469x over previous
//
#include <hip/hip_runtime.h>
#include <hip/hip_bf16.h>

typedef __attribute__((ext_vector_type(8))) __bf16 bf16x8;
typedef __attribute__((ext_vector_type(4))) float f32x4;

#define NB 2

__device__ __forceinline__ unsigned short f2bf(float f) {
    __hip_bfloat16 h = __float2bfloat16(f);
    return *reinterpret_cast<unsigned short*>(&h);
}
__device__ __forceinline__ float bflo(unsigned int u) { return __uint_as_float(u << 16); }
__device__ __forceinline__ float bfhi(unsigned int u) { return __uint_as_float(u & 0xffff0000u); }

__device__ __forceinline__ void gload_lds16(const void* g, void* l) {
    __builtin_amdgcn_global_load_lds(
        (const __attribute__((address_space(1))) unsigned int*)g,
        (__attribute__((address_space(3))) unsigned int*)l, 16, 0, 0);
}

// ---------------------------------------------------------------------------
// xbf: bf16 image of x, per-pixel 512B rows, 16B granules XOR-swizzled by
// (pixel&7)<<4 (bits 4-6). All consumers apply the same XOR on read.
// ---------------------------------------------------------------------------
__global__ __launch_bounds__(256) void xbf_kernel(const float* __restrict__ x,
                                                  unsigned int* __restrict__ xbf) {
    int idx = blockIdx.x * 256 + threadIdx.x;  // granule id, 8192*32
    int p = idx >> 5, g = idx & 31;
    const float4* src = reinterpret_cast<const float4*>(x + ((size_t)p * 256 + g * 8));
    float4 lo = src[0], hi = src[1];
    uint4 o;
    o.x = f2bf(lo.x) | ((unsigned)f2bf(lo.y) << 16);
    o.y = f2bf(lo.z) | ((unsigned)f2bf(lo.w) << 16);
    o.z = f2bf(hi.x) | ((unsigned)f2bf(hi.y) << 16);
    o.w = f2bf(hi.z) | ((unsigned)f2bf(hi.w) << 16);
    int byte = (g * 16) ^ ((p & 7) << 4);
    *reinterpret_cast<uint4*>((char*)xbf + (size_t)p * 512 + byte) = o;
}

// wtb[tap][ch 96][ci 256] bf16, 512B ch-rows swizzled by (ch&7)<<4
__global__ __launch_bounds__(256) void wtb_kernel(const float* __restrict__ ow,
                                                  const float* __restrict__ aw,
                                                  unsigned short* __restrict__ wtb) {
    int o = blockIdx.x * 256 + threadIdx.x;   // (tap*96+ch)*256 + ci
    int ci = o & 255; int t = o >> 8; int ch = t % 96; int tap = t / 96;
    float v = (ch < 64) ? ow[((size_t)ch * 256 + ci) * 9 + tap]
                        : aw[((size_t)(ch - 64) * 256 + ci) * 9 + tap];
    size_t base = (size_t)(tap * 96 + ch) * 512;
    int byte = (2 * ci) ^ ((ch & 7) << 4);
    *reinterpret_cast<unsigned short*>((char*)wtb + base + byte) = f2bf(v);
}

// wob[n 256][k 256] bf16 swizzled by (n&7)<<4
__global__ __launch_bounds__(256) void wob_kernel(const float* __restrict__ wO,
                                                  unsigned short* __restrict__ wob) {
    int o = blockIdx.x * 256 + threadIdx.x;
    int k = o & 255, n = o >> 8;
    int byte = (2 * k) ^ ((n & 7) << 4);
    *reinterpret_cast<unsigned short*>((char*)wob + (size_t)n * 512 + byte) = f2bf(wO[o]);
}

// ---------------------------------------------------------------------------
// conv: implicit-GEMM 3x3 SAME conv. Block = 32 px (half row) x 96 ch.
// 4 waves K-split over ci chunks of 64 (wave w = chunk w); tap-major staging:
//   A = halo row [34 px][512B] (linear copy of pre-swizzled xbf)
//   B = one tap  [96 ch][512B] via global_load_lds (linear, pre-swizzled)
// Epilogue: cross-wave reduce of 32x96 partials in LDS, + bias, store fp32.
// ---------------------------------------------------------------------------
__global__ __launch_bounds__(256, 2) void conv_kernel(const unsigned int* __restrict__ xbf,
                                                      const unsigned short* __restrict__ wtb,
                                                      const float* __restrict__ offb,
                                                      const float* __restrict__ attb,
                                                      float* __restrict__ conv) {
    __shared__ char lds[66560];            // A: 17408 B, B: 49152 B
    char* ldsA = lds;
    char* ldsB = lds + 17408;
    int blk = blockIdx.x;
    int xh = blk & 1, y = (blk >> 1) & 63, b = blk >> 7;
    int x0 = xh * 32;
    int tid = threadIdx.x, wid = tid >> 6, lane = tid & 63;
    int l15 = lane & 15, l7 = lane & 7, hi16 = (lane >> 4) * 16;

    f32x4 acc[2][6];
#pragma unroll
    for (int mf = 0; mf < 2; ++mf)
#pragma unroll
        for (int nf = 0; nf < 6; ++nf) acc[mf][nf] = (f32x4){0.f, 0.f, 0.f, 0.f};

    for (int ky = 0; ky < 3; ++ky) {
        int gy = y + ky - 1;
        __syncthreads();                   // prior tap's A reads done
        for (int g = tid; g < 1088; g += 256) {  // 34 px * 32 granules
            int px = g >> 5, go = g & 31;
            int gx = x0 - 1 + px;
            uint4 v = make_uint4(0, 0, 0, 0);
            if (gy >= 0 && gy < 64 && gx >= 0 && gx < 64) {
                size_t p = (size_t)b * 4096 + gy * 64 + gx;
                v = *reinterpret_cast<const uint4*>((const char*)xbf + p * 512 + go * 16);
            }
            *reinterpret_cast<uint4*>(ldsA + px * 512 + go * 16) = v;
        }
        for (int kx = 0; kx < 3; ++kx) {
            int tap = ky * 3 + kx;
            __syncthreads();               // prior B reads done (also A for kx=0 below)
            const char* bsrc = (const char*)wtb + (size_t)tap * 49152;
            for (int i = 0; i < 12; ++i) { // 3072 granules, wave-chunked
                int g0 = i * 256 + wid * 64;
                gload_lds16(bsrc + (size_t)(g0 + lane) * 16, ldsB + g0 * 16);
            }
            __syncthreads();               // drains vmcnt + lgkm: A and B ready
#pragma unroll
            for (int kk = 0; kk < 2; ++kk) {
                int key = ((l7 + kx + 7) & 7) << 4;   // (gx&7)<<4; x0 % 8 == 0
                int px0 = l15 + kx;
                bf16x8 a0 = *reinterpret_cast<const bf16x8*>(
                    ldsA + px0 * 512 + wid * 128 + ((kk * 64 + hi16) ^ key));
                bf16x8 a1 = *reinterpret_cast<const bf16x8*>(
                    ldsA + (px0 + 16) * 512 + wid * 128 + ((kk * 64 + hi16) ^ key));
#pragma unroll
                for (int nf = 0; nf < 6; ++nf) {
                    int ch = 16 * nf + l15;
                    bf16x8 bv = *reinterpret_cast<const bf16x8*>(
                        ldsB + ch * 512 + wid * 128 + ((kk * 64 + hi16) ^ (l7 << 4)));
                    acc[0][nf] = __builtin_amdgcn_mfma_f32_16x16x32_bf16(a0, bv, acc[0][nf], 0, 0, 0);
                    acc[1][nf] = __builtin_amdgcn_mfma_f32_16x16x32_bf16(a1, bv, acc[1][nf], 0, 0, 0);
                }
            }
        }
    }
    // cross-wave K reduce: part[w][m 32][ch padded 100]
    __syncthreads();
    float* part = reinterpret_cast<float*>(lds);
#pragma unroll
    for (int mf = 0; mf < 2; ++mf)
#pragma unroll
        for (int nf = 0; nf < 6; ++nf)
#pragma unroll
            for (int r = 0; r < 4; ++r) {
                int m = 16 * mf + (lane >> 4) * 4 + r;
                int ch = 16 * nf + l15;
                part[(wid * 32 + m) * 100 + ch] = acc[mf][nf][r];
            }
    __syncthreads();
    int m = tid >> 3, c0 = (tid & 7) * 12;
#pragma unroll
    for (int j = 0; j < 12; ++j) {
        int ch = c0 + j;
        float v = part[m * 100 + ch] + part[(32 + m) * 100 + ch] +
                  part[(64 + m) * 100 + ch] + part[(96 + m) * 100 + ch];
        float bias = (ch < 64) ? offb[ch] : attb[ch - 64];
        conv[(size_t)(b * 96 + ch) * 4096 + y * 64 + x0 + m] = v + bias;
    }
}

// ---------------------------------------------------------------------------
// sample: softmax over p + bilinear gather from bf16 x + head-mean.
// One wave per query; half-wave per sample (lanes 0-31: even s, 32-63: odd s),
// lane covers 8 channels (uint4 = 8 bf16). Writes S bf16, swizzled by (q&7).
// Attn uses spatial (qi,qj), offsets use (qj,qi) — intentional, matches ref.
// ---------------------------------------------------------------------------
__global__ __launch_bounds__(256) void sample_kernel(const unsigned int* __restrict__ xbf,
                                                     const float* __restrict__ conv,
                                                     unsigned int* __restrict__ S) {
    __shared__ float s_coef[4][32][4];
    __shared__ int s_pix[4][32][4];
    int tid = threadIdx.x, wid = tid >> 6, lane = tid & 63;
    int q = blockIdx.x * 4 + wid;
    int b = q >> 12, qi = (q >> 6) & 63, qj = q & 63;
    const float* convb = conv + (size_t)b * 96 * 4096;

    if (lane < 32) {
        int s = lane;
        float logit = convb[(64 + s) * 4096 + qi * 64 + qj];
        float mx = logit;
        mx = fmaxf(mx, __shfl_xor(mx, 1));
        mx = fmaxf(mx, __shfl_xor(mx, 2));
        float e = __expf(logit - mx);
        float sum = e;
        sum += __shfl_xor(sum, 1);
        sum += __shfl_xor(sum, 2);
        float a = e / sum * 0.125f;

        float ox = convb[(2 * s) * 4096 + qj * 64 + qi];
        float oy = convb[(2 * s + 1) * 4096 + qj * 64 + qi];
        float gx = (float)qi * (1.f / 63.f) + 0.1f * ox;
        float gy = (float)qj * (1.f / 63.f) + 0.1f * oy;
        float ix = ((gx + 1.f) * 64.f - 1.f) * 0.5f;
        float iy = ((gy + 1.f) * 64.f - 1.f) * 0.5f;
        float x0f = floorf(ix), y0f = floorf(iy);
        float wx = ix - x0f, wy = iy - y0f;
        int x0 = (int)x0f, y0 = (int)y0f;
#pragma unroll
        for (int c = 0; c < 4; ++c) {
            int xi = x0 + (c & 1), yi = y0 + (c >> 1);
            float w = ((c & 1) ? wx : 1.f - wx) * ((c >> 1) ? wy : 1.f - wy);
            bool valid = (xi >= 0) && (xi < 64) && (yi >= 0) && (yi < 64);
            int xc = min(max(xi, 0), 63), yc = min(max(yi, 0), 63);
            s_coef[wid][s][c] = valid ? a * w : 0.f;
            s_pix[wid][s][c] = yc * 64 + xc;
        }
    }
    __syncthreads();

    const char* xb = (const char*)xbf + (size_t)b * 4096 * 512;
    int half = lane >> 5, l31 = lane & 31;
    float acc[8] = {0.f, 0.f, 0.f, 0.f, 0.f, 0.f, 0.f, 0.f};
    for (int ss = 0; ss < 16; ++ss) {
        int s = ss * 2 + half;
#pragma unroll
        for (int c = 0; c < 4; ++c) {
            float coef = s_coef[wid][s][c];
            if (coef != 0.f) {
                int p = s_pix[wid][s][c];
                uint4 v = *reinterpret_cast<const uint4*>(
                    xb + (size_t)p * 512 + ((l31 * 16) ^ ((p & 7) << 4)));
                acc[0] = fmaf(coef, bflo(v.x), acc[0]);
                acc[1] = fmaf(coef, bfhi(v.x), acc[1]);
                acc[2] = fmaf(coef, bflo(v.y), acc[2]);
                acc[3] = fmaf(coef, bfhi(v.y), acc[3]);
                acc[4] = fmaf(coef, bflo(v.z), acc[4]);
                acc[5] = fmaf(coef, bfhi(v.z), acc[5]);
                acc[6] = fmaf(coef, bflo(v.w), acc[6]);
                acc[7] = fmaf(coef, bfhi(v.w), acc[7]);
            }
        }
    }
#pragma unroll
    for (int i = 0; i < 8; ++i) acc[i] += __shfl_xor(acc[i], 32);
    if (lane < 32) {
        uint4 o;
        o.x = f2bf(acc[0]) | ((unsigned)f2bf(acc[1]) << 16);
        o.y = f2bf(acc[2]) | ((unsigned)f2bf(acc[3]) << 16);
        o.z = f2bf(acc[4]) | ((unsigned)f2bf(acc[5]) << 16);
        o.w = f2bf(acc[6]) | ((unsigned)f2bf(acc[7]) << 16);
        *reinterpret_cast<uint4*>((char*)S + (size_t)q * 512 +
                                  ((l31 * 16) ^ ((q & 7) << 4))) = o;
    }
}

// ---------------------------------------------------------------------------
// gemm: out[m][n] = S[m][k] . wob[n][k] + b[n].  M=8192 N=256 K=256.
// Block 64x64, full-K LDS stage (64KB) via global_load_lds, 4 waves (2Mx2N),
// wave tile 32x32 (2x2 frags x 8 K-frags).
// ---------------------------------------------------------------------------
__global__ __launch_bounds__(256, 2) void gemm_kernel(const char* __restrict__ S,
                                                      const char* __restrict__ wob,
                                                      const float* __restrict__ bO,
                                                      float* __restrict__ out) {
    __shared__ char lds[65536];
    char* ldsA = lds;
    char* ldsB = lds + 32768;
    int bm = blockIdx.x, bn = blockIdx.y;
    int tid = threadIdx.x, wid = tid >> 6, lane = tid & 63;
    int wm = wid >> 1, wn = wid & 1;
    int l15 = lane & 15, l7 = lane & 7, hi16 = (lane >> 4) * 16;
    const char* srcA = S + (size_t)bm * 64 * 512;
    const char* srcB = wob + (size_t)bn * 64 * 512;
    for (int i = 0; i < 8; ++i) {
        int g0 = i * 256 + wid * 64;
        gload_lds16(srcA + (size_t)(g0 + lane) * 16, ldsA + g0 * 16);
        gload_lds16(srcB + (size_t)(g0 + lane) * 16, ldsB + g0 * 16);
    }
    f32x4 acc[2][2];
#pragma unroll
    for (int mf = 0; mf < 2; ++mf)
#pragma unroll
        for (int nf = 0; nf < 2; ++nf) acc[mf][nf] = (f32x4){0.f, 0.f, 0.f, 0.f};
    __syncthreads();
#pragma unroll
    for (int kk = 0; kk < 8; ++kk) {
        bf16x8 a[2], bv[2];
#pragma unroll
        for (int mf = 0; mf < 2; ++mf) {
            int row = 32 * wm + 16 * mf + l15;
            a[mf] = *reinterpret_cast<const bf16x8*>(
                ldsA + row * 512 + ((kk * 64 + hi16) ^ (l7 << 4)));
        }
#pragma unroll
        for (int nf = 0; nf < 2; ++nf) {
            int row = 32 * wn + 16 * nf + l15;
            bv[nf] = *reinterpret_cast<const bf16x8*>(
                ldsB + row * 512 + ((kk * 64 + hi16) ^ (l7 << 4)));
        }
#pragma unroll
        for (int mf = 0; mf < 2; ++mf)
#pragma unroll
            for (int nf = 0; nf < 2; ++nf)
                acc[mf][nf] = __builtin_amdgcn_mfma_f32_16x16x32_bf16(a[mf], bv[nf], acc[mf][nf], 0, 0, 0);
    }
#pragma unroll
    for (int mf = 0; mf < 2; ++mf)
#pragma unroll
        for (int nf = 0; nf < 2; ++nf) {
            int n = bn * 64 + 32 * wn + 16 * nf + l15;
            float bias = bO[n];
#pragma unroll
            for (int r = 0; r < 4; ++r) {
                int m = bm * 64 + 32 * wm + 16 * mf + (lane >> 4) * 4 + r;
                out[(size_t)m * 256 + n] = acc[mf][nf][r] + bias;
            }
        }
}

extern "C" void kernel_launch(void* const* d_in, const int* in_sizes, int n_in,
                              void* d_out, int out_size, void* d_ws, size_t ws_size,
                              hipStream_t stream) {
    const float* x  = (const float*)d_in[0];
    const float* ow = (const float*)d_in[1];
    const float* ob = (const float*)d_in[2];
    const float* aw = (const float*)d_in[3];
    const float* ab = (const float*)d_in[4];
    const float* wO = (const float*)d_in[5];
    const float* bO = (const float*)d_in[6];
    float* out = (float*)d_out;

    char* ws = (char*)d_ws;
    unsigned int*   xbf = (unsigned int*)(ws);                 // 4,194,304 B
    unsigned short* wtb = (unsigned short*)(ws + 4194304);     //   442,368 B
    unsigned short* wob = (unsigned short*)(ws + 4636672);     //   131,072 B
    float*          cnv = (float*)(ws + 4767744);              // 3,145,728 B
    unsigned int*   S   = (unsigned int*)(ws + 7913472);       // 4,194,304 B

    hipLaunchKernelGGL(xbf_kernel, dim3(1024), dim3(256), 0, stream, x, xbf);
    hipLaunchKernelGGL(wtb_kernel, dim3(864), dim3(256), 0, stream, ow, aw, wtb);
    hipLaunchKernelGGL(wob_kernel, dim3(256), dim3(256), 0, stream, wO, wob);
    hipLaunchKernelGGL(conv_kernel, dim3(NB * 64 * 2), dim3(256), 0, stream,
                       xbf, wtb, ob, ab, cnv);
    hipLaunchKernelGGL(sample_kernel, dim3(2048), dim3(256), 0, stream, xbf, cnv, S);
    hipLaunchKernelGGL(gemm_kernel, dim3(128, 4), dim3(256), 0, stream,
                       (const char*)S, (const char*)wob, bO, out);
}

// Round 3
// 123.904 us; speedup vs baseline: 2.2864x; 1.0650x over previous
//
#include <hip/hip_runtime.h>
#include <hip/hip_bf16.h>

typedef __attribute__((ext_vector_type(8))) __bf16 bf16x8;
typedef __attribute__((ext_vector_type(4))) float f32x4;

#define NB 2

__device__ __forceinline__ unsigned short f2bf(float f) {
    __hip_bfloat16 h = __float2bfloat16(f);
    return *reinterpret_cast<unsigned short*>(&h);
}
__device__ __forceinline__ float bflo(unsigned int u) { return __uint_as_float(u << 16); }
__device__ __forceinline__ float bfhi(unsigned int u) { return __uint_as_float(u & 0xffff0000u); }

__device__ __forceinline__ void gload_lds16(const void* g, void* l) {
    __builtin_amdgcn_global_load_lds(
        (const __attribute__((address_space(1))) unsigned int*)g,
        (__attribute__((address_space(3))) unsigned int*)l, 16, 0, 0);
}

// ---------------------------------------------------------------------------
// pack: fused repack of x -> xbf (bf16, 512B pixel rows, 16B granules
// XOR-swizzled by (pixel&7)<<4), conv weights -> wtb, proj weights -> wob.
// One thread per output element; ranges partition the grid.
//   [0, 262144)            xbf granules (8192 px * 32)
//   [262144, 483328)       wtb elements (9*96*256)
//   [483328, 548864)       wob elements (256*256)
// ---------------------------------------------------------------------------
__global__ __launch_bounds__(256) void pack_kernel(const float* __restrict__ x,
                                                   const float* __restrict__ ow,
                                                   const float* __restrict__ aw,
                                                   const float* __restrict__ wO,
                                                   unsigned int* __restrict__ xbf,
                                                   unsigned short* __restrict__ wtb,
                                                   unsigned short* __restrict__ wob) {
    int idx = blockIdx.x * 256 + threadIdx.x;
    if (idx < 262144) {
        int p = idx >> 5, g = idx & 31;
        const float4* src = reinterpret_cast<const float4*>(x + ((size_t)p * 256 + g * 8));
        float4 lo = src[0], hi = src[1];
        uint4 o;
        o.x = f2bf(lo.x) | ((unsigned)f2bf(lo.y) << 16);
        o.y = f2bf(lo.z) | ((unsigned)f2bf(lo.w) << 16);
        o.z = f2bf(hi.x) | ((unsigned)f2bf(hi.y) << 16);
        o.w = f2bf(hi.z) | ((unsigned)f2bf(hi.w) << 16);
        int byte = (g * 16) ^ ((p & 7) << 4);
        *reinterpret_cast<uint4*>((char*)xbf + (size_t)p * 512 + byte) = o;
    } else if (idx < 483328) {
        int o = idx - 262144;              // (tap*96+ch)*256 + ci
        int ci = o & 255; int t = o >> 8; int ch = t % 96; int tap = t / 96;
        float v = (ch < 64) ? ow[((size_t)ch * 256 + ci) * 9 + tap]
                            : aw[((size_t)(ch - 64) * 256 + ci) * 9 + tap];
        size_t base = (size_t)(tap * 96 + ch) * 512;
        int byte = (2 * ci) ^ ((ch & 7) << 4);
        *reinterpret_cast<unsigned short*>((char*)wtb + base + byte) = f2bf(v);
    } else {
        int o = idx - 483328;              // n*256 + k
        int k = o & 255, n = o >> 8;
        int byte = (2 * k) ^ ((n & 7) << 4);
        *reinterpret_cast<unsigned short*>((char*)wob + (size_t)n * 512 + byte) = f2bf(wO[o]);
    }
}

// ---------------------------------------------------------------------------
// conv: implicit-GEMM 3x3 SAME conv (unchanged from round 2 — proven).
// Block = 32 px (half row) x 96 ch; 4 waves K-split over ci chunks of 64.
// ---------------------------------------------------------------------------
__global__ __launch_bounds__(256, 2) void conv_kernel(const unsigned int* __restrict__ xbf,
                                                      const unsigned short* __restrict__ wtb,
                                                      const float* __restrict__ offb,
                                                      const float* __restrict__ attb,
                                                      float* __restrict__ conv) {
    __shared__ char lds[66560];            // A: 17408 B, B: 49152 B
    char* ldsA = lds;
    char* ldsB = lds + 17408;
    int blk = blockIdx.x;
    int xh = blk & 1, y = (blk >> 1) & 63, b = blk >> 7;
    int x0 = xh * 32;
    int tid = threadIdx.x, wid = tid >> 6, lane = tid & 63;
    int l15 = lane & 15, l7 = lane & 7, hi16 = (lane >> 4) * 16;

    f32x4 acc[2][6];
#pragma unroll
    for (int mf = 0; mf < 2; ++mf)
#pragma unroll
        for (int nf = 0; nf < 6; ++nf) acc[mf][nf] = (f32x4){0.f, 0.f, 0.f, 0.f};

    for (int ky = 0; ky < 3; ++ky) {
        int gy = y + ky - 1;
        __syncthreads();                   // prior tap's A reads done
        for (int g = tid; g < 1088; g += 256) {  // 34 px * 32 granules
            int px = g >> 5, go = g & 31;
            int gx = x0 - 1 + px;
            uint4 v = make_uint4(0, 0, 0, 0);
            if (gy >= 0 && gy < 64 && gx >= 0 && gx < 64) {
                size_t p = (size_t)b * 4096 + gy * 64 + gx;
                v = *reinterpret_cast<const uint4*>((const char*)xbf + p * 512 + go * 16);
            }
            *reinterpret_cast<uint4*>(ldsA + px * 512 + go * 16) = v;
        }
        for (int kx = 0; kx < 3; ++kx) {
            int tap = ky * 3 + kx;
            __syncthreads();               // prior B reads done
            const char* bsrc = (const char*)wtb + (size_t)tap * 49152;
            for (int i = 0; i < 12; ++i) { // 3072 granules, wave-chunked
                int g0 = i * 256 + wid * 64;
                gload_lds16(bsrc + (size_t)(g0 + lane) * 16, ldsB + g0 * 16);
            }
            __syncthreads();               // drains vmcnt + lgkm: A and B ready
#pragma unroll
            for (int kk = 0; kk < 2; ++kk) {
                int key = ((l7 + kx + 7) & 7) << 4;   // (gx&7)<<4; x0 % 8 == 0
                int px0 = l15 + kx;
                bf16x8 a0 = *reinterpret_cast<const bf16x8*>(
                    ldsA + px0 * 512 + wid * 128 + ((kk * 64 + hi16) ^ key));
                bf16x8 a1 = *reinterpret_cast<const bf16x8*>(
                    ldsA + (px0 + 16) * 512 + wid * 128 + ((kk * 64 + hi16) ^ key));
#pragma unroll
                for (int nf = 0; nf < 6; ++nf) {
                    int ch = 16 * nf + l15;
                    bf16x8 bv = *reinterpret_cast<const bf16x8*>(
                        ldsB + ch * 512 + wid * 128 + ((kk * 64 + hi16) ^ (l7 << 4)));
                    acc[0][nf] = __builtin_amdgcn_mfma_f32_16x16x32_bf16(a0, bv, acc[0][nf], 0, 0, 0);
                    acc[1][nf] = __builtin_amdgcn_mfma_f32_16x16x32_bf16(a1, bv, acc[1][nf], 0, 0, 0);
                }
            }
        }
    }
    // cross-wave K reduce: part[w][m 32][ch padded 100]
    __syncthreads();
    float* part = reinterpret_cast<float*>(lds);
#pragma unroll
    for (int mf = 0; mf < 2; ++mf)
#pragma unroll
        for (int nf = 0; nf < 6; ++nf)
#pragma unroll
            for (int r = 0; r < 4; ++r) {
                int m = 16 * mf + (lane >> 4) * 4 + r;
                int ch = 16 * nf + l15;
                part[(wid * 32 + m) * 100 + ch] = acc[mf][nf][r];
            }
    __syncthreads();
    int m = tid >> 3, c0 = (tid & 7) * 12;
#pragma unroll
    for (int j = 0; j < 12; ++j) {
        int ch = c0 + j;
        float v = part[m * 100 + ch] + part[(32 + m) * 100 + ch] +
                  part[(64 + m) * 100 + ch] + part[(96 + m) * 100 + ch];
        float bias = (ch < 64) ? offb[ch] : attb[ch - 64];
        conv[(size_t)(b * 96 + ch) * 4096 + y * 64 + x0 + m] = v + bias;
    }
}

// ---------------------------------------------------------------------------
// sample: softmax over p + bilinear gather from bf16 x + head-mean.
// One wave per query; half-wave per sample. BRANCHLESS gather: corner loads
// are unconditional (pixel indices are clamped in-range; invalid corners have
// coef 0), so 4 independent loads issue per iteration and pipeline.
// ---------------------------------------------------------------------------
__global__ __launch_bounds__(256) void sample_kernel(const unsigned int* __restrict__ xbf,
                                                     const float* __restrict__ conv,
                                                     unsigned int* __restrict__ S) {
    __shared__ float s_coef[4][32][4];
    __shared__ int s_pix[4][32][4];
    int tid = threadIdx.x, wid = tid >> 6, lane = tid & 63;
    int q = blockIdx.x * 4 + wid;
    int b = q >> 12, qi = (q >> 6) & 63, qj = q & 63;
    const float* convb = conv + (size_t)b * 96 * 4096;

    if (lane < 32) {
        int s = lane;
        float logit = convb[(64 + s) * 4096 + qi * 64 + qj];
        float mx = logit;
        mx = fmaxf(mx, __shfl_xor(mx, 1));
        mx = fmaxf(mx, __shfl_xor(mx, 2));
        float e = __expf(logit - mx);
        float sum = e;
        sum += __shfl_xor(sum, 1);
        sum += __shfl_xor(sum, 2);
        float a = e / sum * 0.125f;

        float ox = convb[(2 * s) * 4096 + qj * 64 + qi];
        float oy = convb[(2 * s + 1) * 4096 + qj * 64 + qi];
        float gx = (float)qi * (1.f / 63.f) + 0.1f * ox;
        float gy = (float)qj * (1.f / 63.f) + 0.1f * oy;
        float ix = ((gx + 1.f) * 64.f - 1.f) * 0.5f;
        float iy = ((gy + 1.f) * 64.f - 1.f) * 0.5f;
        float x0f = floorf(ix), y0f = floorf(iy);
        float wx = ix - x0f, wy = iy - y0f;
        int x0 = (int)x0f, y0 = (int)y0f;
#pragma unroll
        for (int c = 0; c < 4; ++c) {
            int xi = x0 + (c & 1), yi = y0 + (c >> 1);
            float w = ((c & 1) ? wx : 1.f - wx) * ((c >> 1) ? wy : 1.f - wy);
            bool valid = (xi >= 0) && (xi < 64) && (yi >= 0) && (yi < 64);
            int xc = min(max(xi, 0), 63), yc = min(max(yi, 0), 63);
            s_coef[wid][s][c] = valid ? a * w : 0.f;
            s_pix[wid][s][c] = yc * 64 + xc;
        }
    }
    __syncthreads();

    const char* xb = (const char*)xbf + (size_t)b * 4096 * 512;
    int half = lane >> 5, l31 = lane & 31;
    int lbyte = l31 * 16;
    float acc[8] = {0.f, 0.f, 0.f, 0.f, 0.f, 0.f, 0.f, 0.f};
#pragma unroll 2
    for (int ss = 0; ss < 16; ++ss) {
        int s = ss * 2 + half;
        float4 cf = *reinterpret_cast<const float4*>(&s_coef[wid][s][0]);
        int4 pp = *reinterpret_cast<const int4*>(&s_pix[wid][s][0]);
        uint4 v0 = *reinterpret_cast<const uint4*>(
            xb + (size_t)pp.x * 512 + (lbyte ^ ((pp.x & 7) << 4)));
        uint4 v1 = *reinterpret_cast<const uint4*>(
            xb + (size_t)pp.y * 512 + (lbyte ^ ((pp.y & 7) << 4)));
        uint4 v2 = *reinterpret_cast<const uint4*>(
            xb + (size_t)pp.z * 512 + (lbyte ^ ((pp.z & 7) << 4)));
        uint4 v3 = *reinterpret_cast<const uint4*>(
            xb + (size_t)pp.w * 512 + (lbyte ^ ((pp.w & 7) << 4)));
#define FMA8(COEF, V)                                   \
        acc[0] = fmaf(COEF, bflo(V.x), acc[0]);         \
        acc[1] = fmaf(COEF, bfhi(V.x), acc[1]);         \
        acc[2] = fmaf(COEF, bflo(V.y), acc[2]);         \
        acc[3] = fmaf(COEF, bfhi(V.y), acc[3]);         \
        acc[4] = fmaf(COEF, bflo(V.z), acc[4]);         \
        acc[5] = fmaf(COEF, bfhi(V.z), acc[5]);         \
        acc[6] = fmaf(COEF, bflo(V.w), acc[6]);         \
        acc[7] = fmaf(COEF, bfhi(V.w), acc[7]);
        FMA8(cf.x, v0)
        FMA8(cf.y, v1)
        FMA8(cf.z, v2)
        FMA8(cf.w, v3)
#undef FMA8
    }
#pragma unroll
    for (int i = 0; i < 8; ++i) acc[i] += __shfl_xor(acc[i], 32);
    if (lane < 32) {
        uint4 o;
        o.x = f2bf(acc[0]) | ((unsigned)f2bf(acc[1]) << 16);
        o.y = f2bf(acc[2]) | ((unsigned)f2bf(acc[3]) << 16);
        o.z = f2bf(acc[4]) | ((unsigned)f2bf(acc[5]) << 16);
        o.w = f2bf(acc[6]) | ((unsigned)f2bf(acc[7]) << 16);
        *reinterpret_cast<uint4*>((char*)S + (size_t)q * 512 +
                                  (lbyte ^ ((q & 7) << 4))) = o;
    }
}

// ---------------------------------------------------------------------------
// gemm: out[m][n] = S[m][k] . wob[n][k] + b[n].  M=8192 N=256 K=256.
// (unchanged from round 2 — proven)
// ---------------------------------------------------------------------------
__global__ __launch_bounds__(256, 2) void gemm_kernel(const char* __restrict__ S,
                                                      const char* __restrict__ wob,
                                                      const float* __restrict__ bO,
                                                      float* __restrict__ out) {
    __shared__ char lds[65536];
    char* ldsA = lds;
    char* ldsB = lds + 32768;
    int bm = blockIdx.x, bn = blockIdx.y;
    int tid = threadIdx.x, wid = tid >> 6, lane = tid & 63;
    int wm = wid >> 1, wn = wid & 1;
    int l15 = lane & 15, l7 = lane & 7, hi16 = (lane >> 4) * 16;
    const char* srcA = S + (size_t)bm * 64 * 512;
    const char* srcB = wob + (size_t)bn * 64 * 512;
    for (int i = 0; i < 8; ++i) {
        int g0 = i * 256 + wid * 64;
        gload_lds16(srcA + (size_t)(g0 + lane) * 16, ldsA + g0 * 16);
        gload_lds16(srcB + (size_t)(g0 + lane) * 16, ldsB + g0 * 16);
    }
    f32x4 acc[2][2];
#pragma unroll
    for (int mf = 0; mf < 2; ++mf)
#pragma unroll
        for (int nf = 0; nf < 2; ++nf) acc[mf][nf] = (f32x4){0.f, 0.f, 0.f, 0.f};
    __syncthreads();
#pragma unroll
    for (int kk = 0; kk < 8; ++kk) {
        bf16x8 a[2], bv[2];
#pragma unroll
        for (int mf = 0; mf < 2; ++mf) {
            int row = 32 * wm + 16 * mf + l15;
            a[mf] = *reinterpret_cast<const bf16x8*>(
                ldsA + row * 512 + ((kk * 64 + hi16) ^ (l7 << 4)));
        }
#pragma unroll
        for (int nf = 0; nf < 2; ++nf) {
            int row = 32 * wn + 16 * nf + l15;
            bv[nf] = *reinterpret_cast<const bf16x8*>(
                ldsB + row * 512 + ((kk * 64 + hi16) ^ (l7 << 4)));
        }
#pragma unroll
        for (int mf = 0; mf < 2; ++mf)
#pragma unroll
            for (int nf = 0; nf < 2; ++nf)
                acc[mf][nf] = __builtin_amdgcn_mfma_f32_16x16x32_bf16(a[mf], bv[nf], acc[mf][nf], 0, 0, 0);
    }
#pragma unroll
    for (int mf = 0; mf < 2; ++mf)
#pragma unroll
        for (int nf = 0; nf < 2; ++nf) {
            int n = bn * 64 + 32 * wn + 16 * nf + l15;
            float bias = bO[n];
#pragma unroll
            for (int r = 0; r < 4; ++r) {
                int m = bm * 64 + 32 * wm + 16 * mf + (lane >> 4) * 4 + r;
                out[(size_t)m * 256 + n] = acc[mf][nf][r] + bias;
            }
        }
}

extern "C" void kernel_launch(void* const* d_in, const int* in_sizes, int n_in,
                              void* d_out, int out_size, void* d_ws, size_t ws_size,
                              hipStream_t stream) {
    const float* x  = (const float*)d_in[0];
    const float* ow = (const float*)d_in[1];
    const float* ob = (const float*)d_in[2];
    const float* aw = (const float*)d_in[3];
    const float* ab = (const float*)d_in[4];
    const float* wO = (const float*)d_in[5];
    const float* bO = (const float*)d_in[6];
    float* out = (float*)d_out;

    char* ws = (char*)d_ws;
    unsigned int*   xbf = (unsigned int*)(ws);                 // 4,194,304 B
    unsigned short* wtb = (unsigned short*)(ws + 4194304);     //   442,368 B
    unsigned short* wob = (unsigned short*)(ws + 4636672);     //   131,072 B
    float*          cnv = (float*)(ws + 4767744);              // 3,145,728 B
    unsigned int*   S   = (unsigned int*)(ws + 7913472);       // 4,194,304 B

    hipLaunchKernelGGL(pack_kernel, dim3(2144), dim3(256), 0, stream,
                       x, ow, aw, wO, xbf, wtb, wob);
    hipLaunchKernelGGL(conv_kernel, dim3(NB * 64 * 2), dim3(256), 0, stream,
                       xbf, wtb, ob, ab, cnv);
    hipLaunchKernelGGL(sample_kernel, dim3(2048), dim3(256), 0, stream, xbf, cnv, S);
    hipLaunchKernelGGL(gemm_kernel, dim3(128, 4), dim3(256), 0, stream,
                       (const char*)S, (const char*)wob, bO, out);
}

// Round 6
// 120.568 us; speedup vs baseline: 2.3497x; 1.0277x over previous
//
#include <hip/hip_runtime.h>
#include <hip/hip_bf16.h>

typedef __attribute__((ext_vector_type(8))) __bf16 bf16x8;
typedef __attribute__((ext_vector_type(4))) float f32x4;

#define NB 2

__device__ __forceinline__ unsigned short f2bf(float f) {
    __hip_bfloat16 h = __float2bfloat16(f);
    return *reinterpret_cast<unsigned short*>(&h);
}
__device__ __forceinline__ float bflo(unsigned int u) { return __uint_as_float(u << 16); }
__device__ __forceinline__ float bfhi(unsigned int u) { return __uint_as_float(u & 0xffff0000u); }

__device__ __forceinline__ void gload_lds16(const void* g, void* l) {
    __builtin_amdgcn_global_load_lds(
        (const __attribute__((address_space(1))) unsigned int*)g,
        (__attribute__((address_space(3))) unsigned int*)l, 16, 0, 0);
}

// ---------------------------------------------------------------------------
// pack: fused repack of x -> xbf (bf16, 512B pixel rows, 16B granules
// XOR-swizzled by (pixel&7)<<4), conv weights -> wtb, proj weights -> wob.
// ---------------------------------------------------------------------------
__global__ __launch_bounds__(256) void pack_kernel(const float* __restrict__ x,
                                                   const float* __restrict__ ow,
                                                   const float* __restrict__ aw,
                                                   const float* __restrict__ wO,
                                                   unsigned int* __restrict__ xbf,
                                                   unsigned short* __restrict__ wtb,
                                                   unsigned short* __restrict__ wob) {
    int idx = blockIdx.x * 256 + threadIdx.x;
    if (idx < 262144) {
        int p = idx >> 5, g = idx & 31;
        const float4* src = reinterpret_cast<const float4*>(x + ((size_t)p * 256 + g * 8));
        float4 lo = src[0], hi = src[1];
        uint4 o;
        o.x = f2bf(lo.x) | ((unsigned)f2bf(lo.y) << 16);
        o.y = f2bf(lo.z) | ((unsigned)f2bf(lo.w) << 16);
        o.z = f2bf(hi.x) | ((unsigned)f2bf(hi.y) << 16);
        o.w = f2bf(hi.z) | ((unsigned)f2bf(hi.w) << 16);
        int byte = (g * 16) ^ ((p & 7) << 4);
        *reinterpret_cast<uint4*>((char*)xbf + (size_t)p * 512 + byte) = o;
    } else if (idx < 483328) {
        int o = idx - 262144;              // (tap*96+ch)*256 + ci
        int ci = o & 255; int t = o >> 8; int ch = t % 96; int tap = t / 96;
        float v = (ch < 64) ? ow[((size_t)ch * 256 + ci) * 9 + tap]
                            : aw[((size_t)(ch - 64) * 256 + ci) * 9 + tap];
        size_t base = (size_t)(tap * 96 + ch) * 512;
        int byte = (2 * ci) ^ ((ch & 7) << 4);
        *reinterpret_cast<unsigned short*>((char*)wtb + base + byte) = f2bf(v);
    } else {
        int o = idx - 483328;              // n*256 + k
        int k = o & 255, n = o >> 8;
        int byte = (2 * k) ^ ((n & 7) << 4);
        *reinterpret_cast<unsigned short*>((char*)wob + (size_t)n * 512 + byte) = f2bf(wO[o]);
    }
}

// ---------------------------------------------------------------------------
// conv v4 (grid FIXED to 512): implicit-GEMM 3x3 SAME conv.
// Block = 32 px (half row) x 48 ch -> grid 512 = 2 blocks/CU.
// blk bits: {0:xh, 1-6:y, 7:b, 8:chh}. 4 waves K-split over ci chunks.
// B staging ping-pong double-buffered: after each tap's barrier we ISSUE
// tap+1's global_load_lds, then run tap's MFMAs — the next barrier drains an
// already-landed prefetch.
// ---------------------------------------------------------------------------
__global__ __launch_bounds__(256, 2) void conv_kernel(const unsigned int* __restrict__ xbf,
                                                      const unsigned short* __restrict__ wtb,
                                                      const float* __restrict__ offb,
                                                      const float* __restrict__ attb,
                                                      float* __restrict__ conv) {
    __shared__ char lds[66560];            // A: 17408 B, B: 2 x 24576 B
    char* ldsA = lds;
    char* ldsB0 = lds + 17408;
    char* ldsB1 = lds + 17408 + 24576;
    int blk = blockIdx.x;
    int xh = blk & 1, y = (blk >> 1) & 63, b = (blk >> 7) & 1, chh = (blk >> 8) & 1;
    int x0 = xh * 32, ch0 = chh * 48;
    int tid = threadIdx.x, wid = tid >> 6, lane = tid & 63;
    int l15 = lane & 15, l7 = lane & 7, hi16 = (lane >> 4) * 16;

    f32x4 acc[2][3];
#pragma unroll
    for (int mf = 0; mf < 2; ++mf)
#pragma unroll
        for (int nf = 0; nf < 3; ++nf) acc[mf][nf] = (f32x4){0.f, 0.f, 0.f, 0.f};

#define STAGE_B(DST, TAP)                                                     \
    {                                                                         \
        const char* bsrc = (const char*)wtb + (size_t)((TAP) * 96 + ch0) * 512; \
        for (int i = 0; i < 6; ++i) {                                         \
            int g0 = i * 256 + wid * 64;                                      \
            gload_lds16(bsrc + (size_t)(g0 + lane) * 16, (DST) + g0 * 16);    \
        }                                                                     \
    }

    STAGE_B(ldsB0, 0);                     // prologue prefetch, in flight
    for (int ky = 0; ky < 3; ++ky) {
        int gy = y + ky - 1;
        __syncthreads();                   // prior tap's A reads done
        for (int g = tid; g < 1088; g += 256) {  // 34 px * 32 granules
            int px = g >> 5, go = g & 31;
            int gx = x0 - 1 + px;
            uint4 v = make_uint4(0, 0, 0, 0);
            if (gy >= 0 && gy < 64 && gx >= 0 && gx < 64) {
                size_t p = (size_t)b * 4096 + gy * 64 + gx;
                v = *reinterpret_cast<const uint4*>((const char*)xbf + p * 512 + go * 16);
            }
            *reinterpret_cast<uint4*>(ldsA + px * 512 + go * 16) = v;
        }
        for (int kx = 0; kx < 3; ++kx) {
            int tap = ky * 3 + kx;
            char* bcur = (tap & 1) ? ldsB1 : ldsB0;
            char* bnxt = (tap & 1) ? ldsB0 : ldsB1;
            __syncthreads();               // drains: B[tap] landed, A staged
            if (tap < 8) STAGE_B(bnxt, tap + 1);   // fly under this tap's MFMA
#pragma unroll
            for (int kk = 0; kk < 2; ++kk) {
                int key = ((l7 + kx + 7) & 7) << 4;   // (gx&7)<<4; x0 % 8 == 0
                int px0 = l15 + kx;
                bf16x8 a0 = *reinterpret_cast<const bf16x8*>(
                    ldsA + px0 * 512 + wid * 128 + ((kk * 64 + hi16) ^ key));
                bf16x8 a1 = *reinterpret_cast<const bf16x8*>(
                    ldsA + (px0 + 16) * 512 + wid * 128 + ((kk * 64 + hi16) ^ key));
#pragma unroll
                for (int nf = 0; nf < 3; ++nf) {
                    int ch = 16 * nf + l15;
                    bf16x8 bv = *reinterpret_cast<const bf16x8*>(
                        bcur + ch * 512 + wid * 128 + ((kk * 64 + hi16) ^ (l7 << 4)));
                    acc[0][nf] = __builtin_amdgcn_mfma_f32_16x16x32_bf16(a0, bv, acc[0][nf], 0, 0, 0);
                    acc[1][nf] = __builtin_amdgcn_mfma_f32_16x16x32_bf16(a1, bv, acc[1][nf], 0, 0, 0);
                }
            }
        }
    }
#undef STAGE_B
    // cross-wave K reduce: part[w][m 32][ch padded 52]
    __syncthreads();
    float* part = reinterpret_cast<float*>(lds);
#pragma unroll
    for (int mf = 0; mf < 2; ++mf)
#pragma unroll
        for (int nf = 0; nf < 3; ++nf)
#pragma unroll
            for (int r = 0; r < 4; ++r) {
                int m = 16 * mf + (lane >> 4) * 4 + r;
                int ch = 16 * nf + l15;
                part[(wid * 32 + m) * 52 + ch] = acc[mf][nf][r];
            }
    __syncthreads();
    int m = tid >> 3, c0 = (tid & 7) * 6;
#pragma unroll
    for (int j = 0; j < 6; ++j) {
        int ch = c0 + j;
        float v = part[m * 52 + ch] + part[(32 + m) * 52 + ch] +
                  part[(64 + m) * 52 + ch] + part[(96 + m) * 52 + ch];
        int chg = ch0 + ch;
        float bias = (chg < 64) ? offb[chg] : attb[chg - 64];
        conv[(size_t)(b * 96 + chg) * 4096 + y * 64 + x0 + m] = v + bias;
    }
}

// ---------------------------------------------------------------------------
// sample: softmax over p + bilinear gather from bf16 x + head-mean.
// (unchanged from round 3)
// ---------------------------------------------------------------------------
__global__ __launch_bounds__(256) void sample_kernel(const unsigned int* __restrict__ xbf,
                                                     const float* __restrict__ conv,
                                                     unsigned int* __restrict__ S) {
    __shared__ float s_coef[4][32][4];
    __shared__ int s_pix[4][32][4];
    int tid = threadIdx.x, wid = tid >> 6, lane = tid & 63;
    int q = blockIdx.x * 4 + wid;
    int b = q >> 12, qi = (q >> 6) & 63, qj = q & 63;
    const float* convb = conv + (size_t)b * 96 * 4096;

    if (lane < 32) {
        int s = lane;
        float logit = convb[(64 + s) * 4096 + qi * 64 + qj];
        float mx = logit;
        mx = fmaxf(mx, __shfl_xor(mx, 1));
        mx = fmaxf(mx, __shfl_xor(mx, 2));
        float e = __expf(logit - mx);
        float sum = e;
        sum += __shfl_xor(sum, 1);
        sum += __shfl_xor(sum, 2);
        float a = e / sum * 0.125f;

        float ox = convb[(2 * s) * 4096 + qj * 64 + qi];
        float oy = convb[(2 * s + 1) * 4096 + qj * 64 + qi];
        float gx = (float)qi * (1.f / 63.f) + 0.1f * ox;
        float gy = (float)qj * (1.f / 63.f) + 0.1f * oy;
        float ix = ((gx + 1.f) * 64.f - 1.f) * 0.5f;
        float iy = ((gy + 1.f) * 64.f - 1.f) * 0.5f;
        float x0f = floorf(ix), y0f = floorf(iy);
        float wx = ix - x0f, wy = iy - y0f;
        int x0 = (int)x0f, y0 = (int)y0f;
#pragma unroll
        for (int c = 0; c < 4; ++c) {
            int xi = x0 + (c & 1), yi = y0 + (c >> 1);
            float w = ((c & 1) ? wx : 1.f - wx) * ((c >> 1) ? wy : 1.f - wy);
            bool valid = (xi >= 0) && (xi < 64) && (yi >= 0) && (yi < 64);
            int xc = min(max(xi, 0), 63), yc = min(max(yi, 0), 63);
            s_coef[wid][s][c] = valid ? a * w : 0.f;
            s_pix[wid][s][c] = yc * 64 + xc;
        }
    }
    __syncthreads();

    const char* xb = (const char*)xbf + (size_t)b * 4096 * 512;
    int half = lane >> 5, l31 = lane & 31;
    int lbyte = l31 * 16;
    float acc[8] = {0.f, 0.f, 0.f, 0.f, 0.f, 0.f, 0.f, 0.f};
#pragma unroll 2
    for (int ss = 0; ss < 16; ++ss) {
        int s = ss * 2 + half;
        float4 cf = *reinterpret_cast<const float4*>(&s_coef[wid][s][0]);
        int4 pp = *reinterpret_cast<const int4*>(&s_pix[wid][s][0]);
        uint4 v0 = *reinterpret_cast<const uint4*>(
            xb + (size_t)pp.x * 512 + (lbyte ^ ((pp.x & 7) << 4)));
        uint4 v1 = *reinterpret_cast<const uint4*>(
            xb + (size_t)pp.y * 512 + (lbyte ^ ((pp.y & 7) << 4)));
        uint4 v2 = *reinterpret_cast<const uint4*>(
            xb + (size_t)pp.z * 512 + (lbyte ^ ((pp.z & 7) << 4)));
        uint4 v3 = *reinterpret_cast<const uint4*>(
            xb + (size_t)pp.w * 512 + (lbyte ^ ((pp.w & 7) << 4)));
#define FMA8(COEF, V)                                   \
        acc[0] = fmaf(COEF, bflo(V.x), acc[0]);         \
        acc[1] = fmaf(COEF, bfhi(V.x), acc[1]);         \
        acc[2] = fmaf(COEF, bflo(V.y), acc[2]);         \
        acc[3] = fmaf(COEF, bfhi(V.y), acc[3]);         \
        acc[4] = fmaf(COEF, bflo(V.z), acc[4]);         \
        acc[5] = fmaf(COEF, bfhi(V.z), acc[5]);         \
        acc[6] = fmaf(COEF, bflo(V.w), acc[6]);         \
        acc[7] = fmaf(COEF, bfhi(V.w), acc[7]);
        FMA8(cf.x, v0)
        FMA8(cf.y, v1)
        FMA8(cf.z, v2)
        FMA8(cf.w, v3)
#undef FMA8
    }
#pragma unroll
    for (int i = 0; i < 8; ++i) acc[i] += __shfl_xor(acc[i], 32);
    if (lane < 32) {
        uint4 o;
        o.x = f2bf(acc[0]) | ((unsigned)f2bf(acc[1]) << 16);
        o.y = f2bf(acc[2]) | ((unsigned)f2bf(acc[3]) << 16);
        o.z = f2bf(acc[4]) | ((unsigned)f2bf(acc[5]) << 16);
        o.w = f2bf(acc[6]) | ((unsigned)f2bf(acc[7]) << 16);
        *reinterpret_cast<uint4*>((char*)S + (size_t)q * 512 +
                                  (lbyte ^ ((q & 7) << 4))) = o;
    }
}

// ---------------------------------------------------------------------------
// gemm: out[m][n] = S[m][k] . wob[n][k] + b[n].  M=8192 N=256 K=256.
// (unchanged from round 2 — proven)
// ---------------------------------------------------------------------------
__global__ __launch_bounds__(256, 2) void gemm_kernel(const char* __restrict__ S,
                                                      const char* __restrict__ wob,
                                                      const float* __restrict__ bO,
                                                      float* __restrict__ out) {
    __shared__ char lds[65536];
    char* ldsA = lds;
    char* ldsB = lds + 32768;
    int bm = blockIdx.x, bn = blockIdx.y;
    int tid = threadIdx.x, wid = tid >> 6, lane = tid & 63;
    int wm = wid >> 1, wn = wid & 1;
    int l15 = lane & 15, l7 = lane & 7, hi16 = (lane >> 4) * 16;
    const char* srcA = S + (size_t)bm * 64 * 512;
    const char* srcB = wob + (size_t)bn * 64 * 512;
    for (int i = 0; i < 8; ++i) {
        int g0 = i * 256 + wid * 64;
        gload_lds16(srcA + (size_t)(g0 + lane) * 16, ldsA + g0 * 16);
        gload_lds16(srcB + (size_t)(g0 + lane) * 16, ldsB + g0 * 16);
    }
    f32x4 acc[2][2];
#pragma unroll
    for (int mf = 0; mf < 2; ++mf)
#pragma unroll
        for (int nf = 0; nf < 2; ++nf) acc[mf][nf] = (f32x4){0.f, 0.f, 0.f, 0.f};
    __syncthreads();
#pragma unroll
    for (int kk = 0; kk < 8; ++kk) {
        bf16x8 a[2], bv[2];
#pragma unroll
        for (int mf = 0; mf < 2; ++mf) {
            int row = 32 * wm + 16 * mf + l15;
            a[mf] = *reinterpret_cast<const bf16x8*>(
                ldsA + row * 512 + ((kk * 64 + hi16) ^ (l7 << 4)));
        }
#pragma unroll
        for (int nf = 0; nf < 2; ++nf) {
            int row = 32 * wn + 16 * nf + l15;
            bv[nf] = *reinterpret_cast<const bf16x8*>(
                ldsB + row * 512 + ((kk * 64 + hi16) ^ (l7 << 4)));
        }
#pragma unroll
        for (int mf = 0; mf < 2; ++mf)
#pragma unroll
            for (int nf = 0; nf < 2; ++nf)
                acc[mf][nf] = __builtin_amdgcn_mfma_f32_16x16x32_bf16(a[mf], bv[nf], acc[mf][nf], 0, 0, 0);
    }
#pragma unroll
    for (int mf = 0; mf < 2; ++mf)
#pragma unroll
        for (int nf = 0; nf < 2; ++nf) {
            int n = bn * 64 + 32 * wn + 16 * nf + l15;
            float bias = bO[n];
#pragma unroll
            for (int r = 0; r < 4; ++r) {
                int m = bm * 64 + 32 * wm + 16 * mf + (lane >> 4) * 4 + r;
                out[(size_t)m * 256 + n] = acc[mf][nf][r] + bias;
            }
        }
}

extern "C" void kernel_launch(void* const* d_in, const int* in_sizes, int n_in,
                              void* d_out, int out_size, void* d_ws, size_t ws_size,
                              hipStream_t stream) {
    const float* x  = (const float*)d_in[0];
    const float* ow = (const float*)d_in[1];
    const float* ob = (const float*)d_in[2];
    const float* aw = (const float*)d_in[3];
    const float* ab = (const float*)d_in[4];
    const float* wO = (const float*)d_in[5];
    const float* bO = (const float*)d_in[6];
    float* out = (float*)d_out;

    char* ws = (char*)d_ws;
    unsigned int*   xbf = (unsigned int*)(ws);                 // 4,194,304 B
    unsigned short* wtb = (unsigned short*)(ws + 4194304);     //   442,368 B
    unsigned short* wob = (unsigned short*)(ws + 4636672);     //   131,072 B
    float*          cnv = (float*)(ws + 4767744);              // 3,145,728 B
    unsigned int*   S   = (unsigned int*)(ws + 7913472);       // 4,194,304 B

    hipLaunchKernelGGL(pack_kernel, dim3(2144), dim3(256), 0, stream,
                       x, ow, aw, wO, xbf, wtb, wob);
    hipLaunchKernelGGL(conv_kernel, dim3(512), dim3(256), 0, stream,
                       xbf, wtb, ob, ab, cnv);
    hipLaunchKernelGGL(sample_kernel, dim3(2048), dim3(256), 0, stream, xbf, cnv, S);
    hipLaunchKernelGGL(gemm_kernel, dim3(128, 4), dim3(256), 0, stream,
                       (const char*)S, (const char*)wob, bO, out);
}

// Round 9
// 117.852 us; speedup vs baseline: 2.4038x; 1.0230x over previous
//
#include <hip/hip_runtime.h>
#include <hip/hip_bf16.h>

typedef __attribute__((ext_vector_type(8))) __bf16 bf16x8;
typedef __attribute__((ext_vector_type(4))) float f32x4;

#define NB 2

__device__ __forceinline__ unsigned short f2bf(float f) {
    __hip_bfloat16 h = __float2bfloat16(f);
    return *reinterpret_cast<unsigned short*>(&h);
}
__device__ __forceinline__ float bflo(unsigned int u) { return __uint_as_float(u << 16); }
__device__ __forceinline__ float bfhi(unsigned int u) { return __uint_as_float(u & 0xffff0000u); }

__device__ __forceinline__ void gload_lds16(const void* g, void* l) {
    __builtin_amdgcn_global_load_lds(
        (const __attribute__((address_space(1))) unsigned int*)g,
        (__attribute__((address_space(3))) unsigned int*)l, 16, 0, 0);
}

// ---------------------------------------------------------------------------
// pack: fused repack of x -> xbf (bf16, 512B pixel rows, 16B granules
// XOR-swizzled by (pixel&7)<<4), conv weights -> wtb, proj weights -> wob.
// (unchanged)
// ---------------------------------------------------------------------------
__global__ __launch_bounds__(256) void pack_kernel(const float* __restrict__ x,
                                                   const float* __restrict__ ow,
                                                   const float* __restrict__ aw,
                                                   const float* __restrict__ wO,
                                                   unsigned int* __restrict__ xbf,
                                                   unsigned short* __restrict__ wtb,
                                                   unsigned short* __restrict__ wob) {
    int idx = blockIdx.x * 256 + threadIdx.x;
    if (idx < 262144) {
        int p = idx >> 5, g = idx & 31;
        const float4* src = reinterpret_cast<const float4*>(x + ((size_t)p * 256 + g * 8));
        float4 lo = src[0], hi = src[1];
        uint4 o;
        o.x = f2bf(lo.x) | ((unsigned)f2bf(lo.y) << 16);
        o.y = f2bf(lo.z) | ((unsigned)f2bf(lo.w) << 16);
        o.z = f2bf(hi.x) | ((unsigned)f2bf(hi.y) << 16);
        o.w = f2bf(hi.z) | ((unsigned)f2bf(hi.w) << 16);
        int byte = (g * 16) ^ ((p & 7) << 4);
        *reinterpret_cast<uint4*>((char*)xbf + (size_t)p * 512 + byte) = o;
    } else if (idx < 483328) {
        int o = idx - 262144;              // (tap*96+ch)*256 + ci
        int ci = o & 255; int t = o >> 8; int ch = t % 96; int tap = t / 96;
        float v = (ch < 64) ? ow[((size_t)ch * 256 + ci) * 9 + tap]
                            : aw[((size_t)(ch - 64) * 256 + ci) * 9 + tap];
        size_t base = (size_t)(tap * 96 + ch) * 512;
        int byte = (2 * ci) ^ ((ch & 7) << 4);
        *reinterpret_cast<unsigned short*>((char*)wtb + base + byte) = f2bf(v);
    } else {
        int o = idx - 483328;              // n*256 + k
        int k = o & 255, n = o >> 8;
        int byte = (2 * k) ^ ((n & 7) << 4);
        *reinterpret_cast<unsigned short*>((char*)wob + (size_t)n * 512 + byte) = f2bf(wO[o]);
    }
}

// ---------------------------------------------------------------------------
// conv v4 (unchanged from round 6 — proven): implicit-GEMM 3x3 SAME conv.
// Block = 32 px x 48 ch, grid 512, ping-pong B prefetch.
// ---------------------------------------------------------------------------
__global__ __launch_bounds__(256, 2) void conv_kernel(const unsigned int* __restrict__ xbf,
                                                      const unsigned short* __restrict__ wtb,
                                                      const float* __restrict__ offb,
                                                      const float* __restrict__ attb,
                                                      float* __restrict__ conv) {
    __shared__ char lds[66560];            // A: 17408 B, B: 2 x 24576 B
    char* ldsA = lds;
    char* ldsB0 = lds + 17408;
    char* ldsB1 = lds + 17408 + 24576;
    int blk = blockIdx.x;
    int xh = blk & 1, y = (blk >> 1) & 63, b = (blk >> 7) & 1, chh = (blk >> 8) & 1;
    int x0 = xh * 32, ch0 = chh * 48;
    int tid = threadIdx.x, wid = tid >> 6, lane = tid & 63;
    int l15 = lane & 15, l7 = lane & 7, hi16 = (lane >> 4) * 16;

    f32x4 acc[2][3];
#pragma unroll
    for (int mf = 0; mf < 2; ++mf)
#pragma unroll
        for (int nf = 0; nf < 3; ++nf) acc[mf][nf] = (f32x4){0.f, 0.f, 0.f, 0.f};

#define STAGE_B(DST, TAP)                                                     \
    {                                                                         \
        const char* bsrc = (const char*)wtb + (size_t)((TAP) * 96 + ch0) * 512; \
        for (int i = 0; i < 6; ++i) {                                         \
            int g0 = i * 256 + wid * 64;                                      \
            gload_lds16(bsrc + (size_t)(g0 + lane) * 16, (DST) + g0 * 16);    \
        }                                                                     \
    }

    STAGE_B(ldsB0, 0);                     // prologue prefetch, in flight
    for (int ky = 0; ky < 3; ++ky) {
        int gy = y + ky - 1;
        __syncthreads();                   // prior tap's A reads done
        for (int g = tid; g < 1088; g += 256) {  // 34 px * 32 granules
            int px = g >> 5, go = g & 31;
            int gx = x0 - 1 + px;
            uint4 v = make_uint4(0, 0, 0, 0);
            if (gy >= 0 && gy < 64 && gx >= 0 && gx < 64) {
                size_t p = (size_t)b * 4096 + gy * 64 + gx;
                v = *reinterpret_cast<const uint4*>((const char*)xbf + p * 512 + go * 16);
            }
            *reinterpret_cast<uint4*>(ldsA + px * 512 + go * 16) = v;
        }
        for (int kx = 0; kx < 3; ++kx) {
            int tap = ky * 3 + kx;
            char* bcur = (tap & 1) ? ldsB1 : ldsB0;
            char* bnxt = (tap & 1) ? ldsB0 : ldsB1;
            __syncthreads();               // drains: B[tap] landed, A staged
            if (tap < 8) STAGE_B(bnxt, tap + 1);   // fly under this tap's MFMA
#pragma unroll
            for (int kk = 0; kk < 2; ++kk) {
                int key = ((l7 + kx + 7) & 7) << 4;   // (gx&7)<<4; x0 % 8 == 0
                int px0 = l15 + kx;
                bf16x8 a0 = *reinterpret_cast<const bf16x8*>(
                    ldsA + px0 * 512 + wid * 128 + ((kk * 64 + hi16) ^ key));
                bf16x8 a1 = *reinterpret_cast<const bf16x8*>(
                    ldsA + (px0 + 16) * 512 + wid * 128 + ((kk * 64 + hi16) ^ key));
#pragma unroll
                for (int nf = 0; nf < 3; ++nf) {
                    int ch = 16 * nf + l15;
                    bf16x8 bv = *reinterpret_cast<const bf16x8*>(
                        bcur + ch * 512 + wid * 128 + ((kk * 64 + hi16) ^ (l7 << 4)));
                    acc[0][nf] = __builtin_amdgcn_mfma_f32_16x16x32_bf16(a0, bv, acc[0][nf], 0, 0, 0);
                    acc[1][nf] = __builtin_amdgcn_mfma_f32_16x16x32_bf16(a1, bv, acc[1][nf], 0, 0, 0);
                }
            }
        }
    }
#undef STAGE_B
    // cross-wave K reduce: part[w][m 32][ch padded 52]
    __syncthreads();
    float* part = reinterpret_cast<float*>(lds);
#pragma unroll
    for (int mf = 0; mf < 2; ++mf)
#pragma unroll
        for (int nf = 0; nf < 3; ++nf)
#pragma unroll
            for (int r = 0; r < 4; ++r) {
                int m = 16 * mf + (lane >> 4) * 4 + r;
                int ch = 16 * nf + l15;
                part[(wid * 32 + m) * 52 + ch] = acc[mf][nf][r];
            }
    __syncthreads();
    int m = tid >> 3, c0 = (tid & 7) * 6;
#pragma unroll
    for (int j = 0; j < 6; ++j) {
        int ch = c0 + j;
        float v = part[m * 52 + ch] + part[(32 + m) * 52 + ch] +
                  part[(64 + m) * 52 + ch] + part[(96 + m) * 52 + ch];
        int chg = ch0 + ch;
        float bias = (chg < 64) ? offb[chg] : attb[chg - 64];
        conv[(size_t)(b * 96 + chg) * 4096 + y * 64 + x0 + m] = v + bias;
    }
}

// ---------------------------------------------------------------------------
// sample v3: softmax over p + bilinear gather + head-mean.
//  (1) coef phase uses ALL 64 lanes: lane = {s 0..31} x {corner-pair 0..1}.
//  (2) s_pix stores the PRE-SWIZZLED byte offset A = pix*512 | ((pix&7)<<4);
//      per-corner address is (A ^ lbyte) — fields disjoint, so
//      A^lbyte == pix*512 + (lbyte ^ key).
// ---------------------------------------------------------------------------
__global__ __launch_bounds__(256) void sample_kernel(const unsigned int* __restrict__ xbf,
                                                     const float* __restrict__ conv,
                                                     unsigned int* __restrict__ S) {
    __shared__ float s_coef[4][32][4];
    __shared__ int s_pix[4][32][4];
    int tid = threadIdx.x, wid = tid >> 6, lane = tid & 63;
    int q = blockIdx.x * 4 + wid;
    int b = q >> 12, qi = (q >> 6) & 63, qj = q & 63;
    const float* convb = conv + (size_t)b * 96 * 4096;

    {
        int s = lane & 31, cp = lane >> 5;       // cp: corner pair {0,1},{2,3}
        float logit = convb[(64 + s) * 4096 + qi * 64 + qj];
        float mx = logit;
        mx = fmaxf(mx, __shfl_xor(mx, 1));
        mx = fmaxf(mx, __shfl_xor(mx, 2));
        float e = __expf(logit - mx);
        float sum = e;
        sum += __shfl_xor(sum, 1);
        sum += __shfl_xor(sum, 2);
        float a = e / sum * 0.125f;

        float ox = convb[(2 * s) * 4096 + qj * 64 + qi];
        float oy = convb[(2 * s + 1) * 4096 + qj * 64 + qi];
        float gx = (float)qi * (1.f / 63.f) + 0.1f * ox;
        float gy = (float)qj * (1.f / 63.f) + 0.1f * oy;
        float ix = ((gx + 1.f) * 64.f - 1.f) * 0.5f;
        float iy = ((gy + 1.f) * 64.f - 1.f) * 0.5f;
        float x0f = floorf(ix), y0f = floorf(iy);
        float wx = ix - x0f, wy = iy - y0f;
        int x0 = (int)x0f, y0 = (int)y0f;
#pragma unroll
        for (int i = 0; i < 2; ++i) {
            int c = cp * 2 + i;
            int xi = x0 + (c & 1), yi = y0 + (c >> 1);
            float w = ((c & 1) ? wx : 1.f - wx) * ((c >> 1) ? wy : 1.f - wy);
            bool valid = (xi >= 0) && (xi < 64) && (yi >= 0) && (yi < 64);
            int xc = min(max(xi, 0), 63), yc = min(max(yi, 0), 63);
            int pix = yc * 64 + xc;
            s_coef[wid][s][c] = valid ? a * w : 0.f;
            s_pix[wid][s][c] = pix * 512 + ((pix & 7) << 4);  // pre-swizzled
        }
    }
    __syncthreads();

    const char* xb = (const char*)xbf + (size_t)b * 4096 * 512;
    int half = lane >> 5, l31 = lane & 31;
    int lbyte = l31 * 16;
    float acc[8] = {0.f, 0.f, 0.f, 0.f, 0.f, 0.f, 0.f, 0.f};
#pragma unroll 2
    for (int ss = 0; ss < 16; ++ss) {
        int s = ss * 2 + half;
        float4 cf = *reinterpret_cast<const float4*>(&s_coef[wid][s][0]);
        int4 pp = *reinterpret_cast<const int4*>(&s_pix[wid][s][0]);
        uint4 v0 = *reinterpret_cast<const uint4*>(xb + (unsigned)(pp.x ^ lbyte));
        uint4 v1 = *reinterpret_cast<const uint4*>(xb + (unsigned)(pp.y ^ lbyte));
        uint4 v2 = *reinterpret_cast<const uint4*>(xb + (unsigned)(pp.z ^ lbyte));
        uint4 v3 = *reinterpret_cast<const uint4*>(xb + (unsigned)(pp.w ^ lbyte));
#define FMA8(COEF, V)                                   \
        acc[0] = fmaf(COEF, bflo(V.x), acc[0]);         \
        acc[1] = fmaf(COEF, bfhi(V.x), acc[1]);         \
        acc[2] = fmaf(COEF, bflo(V.y), acc[2]);         \
        acc[3] = fmaf(COEF, bfhi(V.y), acc[3]);         \
        acc[4] = fmaf(COEF, bflo(V.z), acc[4]);         \
        acc[5] = fmaf(COEF, bfhi(V.z), acc[5]);         \
        acc[6] = fmaf(COEF, bflo(V.w), acc[6]);         \
        acc[7] = fmaf(COEF, bfhi(V.w), acc[7]);
        FMA8(cf.x, v0)
        FMA8(cf.y, v1)
        FMA8(cf.z, v2)
        FMA8(cf.w, v3)
#undef FMA8
    }
#pragma unroll
    for (int i = 0; i < 8; ++i) acc[i] += __shfl_xor(acc[i], 32);
    if (lane < 32) {
        uint4 o;
        o.x = f2bf(acc[0]) | ((unsigned)f2bf(acc[1]) << 16);
        o.y = f2bf(acc[2]) | ((unsigned)f2bf(acc[3]) << 16);
        o.z = f2bf(acc[4]) | ((unsigned)f2bf(acc[5]) << 16);
        o.w = f2bf(acc[6]) | ((unsigned)f2bf(acc[7]) << 16);
        *reinterpret_cast<uint4*>((char*)S + (size_t)q * 512 +
                                  (lbyte ^ ((q & 7) << 4))) = o;
    }
}

// ---------------------------------------------------------------------------
// gemm: out[m][n] = S[m][k] . wob[n][k] + b[n].  M=8192 N=256 K=256.
// (unchanged — proven)
// ---------------------------------------------------------------------------
__global__ __launch_bounds__(256, 2) void gemm_kernel(const char* __restrict__ S,
                                                      const char* __restrict__ wob,
                                                      const float* __restrict__ bO,
                                                      float* __restrict__ out) {
    __shared__ char lds[65536];
    char* ldsA = lds;
    char* ldsB = lds + 32768;
    int bm = blockIdx.x, bn = blockIdx.y;
    int tid = threadIdx.x, wid = tid >> 6, lane = tid & 63;
    int wm = wid >> 1, wn = wid & 1;
    int l15 = lane & 15, l7 = lane & 7, hi16 = (lane >> 4) * 16;
    const char* srcA = S + (size_t)bm * 64 * 512;
    const char* srcB = wob + (size_t)bn * 64 * 512;
    for (int i = 0; i < 8; ++i) {
        int g0 = i * 256 + wid * 64;
        gload_lds16(srcA + (size_t)(g0 + lane) * 16, ldsA + g0 * 16);
        gload_lds16(srcB + (size_t)(g0 + lane) * 16, ldsB + g0 * 16);
    }
    f32x4 acc[2][2];
#pragma unroll
    for (int mf = 0; mf < 2; ++mf)
#pragma unroll
        for (int nf = 0; nf < 2; ++nf) acc[mf][nf] = (f32x4){0.f, 0.f, 0.f, 0.f};
    __syncthreads();
#pragma unroll
    for (int kk = 0; kk < 8; ++kk) {
        bf16x8 a[2], bv[2];
#pragma unroll
        for (int mf = 0; mf < 2; ++mf) {
            int row = 32 * wm + 16 * mf + l15;
            a[mf] = *reinterpret_cast<const bf16x8*>(
                ldsA + row * 512 + ((kk * 64 + hi16) ^ (l7 << 4)));
        }
#pragma unroll
        for (int nf = 0; nf < 2; ++nf) {
            int row = 32 * wn + 16 * nf + l15;
            bv[nf] = *reinterpret_cast<const bf16x8*>(
                ldsB + row * 512 + ((kk * 64 + hi16) ^ (l7 << 4)));
        }
#pragma unroll
        for (int mf = 0; mf < 2; ++mf)
#pragma unroll
            for (int nf = 0; nf < 2; ++nf)
                acc[mf][nf] = __builtin_amdgcn_mfma_f32_16x16x32_bf16(a[mf], bv[nf], acc[mf][nf], 0, 0, 0);
    }
#pragma unroll
    for (int mf = 0; mf < 2; ++mf)
#pragma unroll
        for (int nf = 0; nf < 2; ++nf) {
            int n = bn * 64 + 32 * wn + 16 * nf + l15;
            float bias = bO[n];
#pragma unroll
            for (int r = 0; r < 4; ++r) {
                int m = bm * 64 + 32 * wm + 16 * mf + (lane >> 4) * 4 + r;
                out[(size_t)m * 256 + n] = acc[mf][nf][r] + bias;
            }
        }
}

extern "C" void kernel_launch(void* const* d_in, const int* in_sizes, int n_in,
                              void* d_out, int out_size, void* d_ws, size_t ws_size,
                              hipStream_t stream) {
    const float* x  = (const float*)d_in[0];
    const float* ow = (const float*)d_in[1];
    const float* ob = (const float*)d_in[2];
    const float* aw = (const float*)d_in[3];
    const float* ab = (const float*)d_in[4];
    const float* wO = (const float*)d_in[5];
    const float* bO = (const float*)d_in[6];
    float* out = (float*)d_out;

    char* ws = (char*)d_ws;
    unsigned int*   xbf = (unsigned int*)(ws);                 // 4,194,304 B
    unsigned short* wtb = (unsigned short*)(ws + 4194304);     //   442,368 B
    unsigned short* wob = (unsigned short*)(ws + 4636672);     //   131,072 B
    float*          cnv = (float*)(ws + 4767744);              // 3,145,728 B
    unsigned int*   S   = (unsigned int*)(ws + 7913472);       // 4,194,304 B

    hipLaunchKernelGGL(pack_kernel, dim3(2144), dim3(256), 0, stream,
                       x, ow, aw, wO, xbf, wtb, wob);
    hipLaunchKernelGGL(conv_kernel, dim3(512), dim3(256), 0, stream,
                       xbf, wtb, ob, ab, cnv);
    hipLaunchKernelGGL(sample_kernel, dim3(2048), dim3(256), 0, stream, xbf, cnv, S);
    hipLaunchKernelGGL(gemm_kernel, dim3(128, 4), dim3(256), 0, stream,
                       (const char*)S, (const char*)wob, bO, out);
}

// Round 10
// 115.220 us; speedup vs baseline: 2.4587x; 1.0228x over previous
//
#include <hip/hip_runtime.h>
#include <hip/hip_bf16.h>

typedef __attribute__((ext_vector_type(8))) __bf16 bf16x8;
typedef __attribute__((ext_vector_type(4))) float f32x4;

#define NB 2

__device__ __forceinline__ unsigned short f2bf(float f) {
    __hip_bfloat16 h = __float2bfloat16(f);
    return *reinterpret_cast<unsigned short*>(&h);
}
__device__ __forceinline__ float bflo(unsigned int u) { return __uint_as_float(u << 16); }
__device__ __forceinline__ float bfhi(unsigned int u) { return __uint_as_float(u & 0xffff0000u); }

__device__ __forceinline__ void gload_lds16(const void* g, void* l) {
    __builtin_amdgcn_global_load_lds(
        (const __attribute__((address_space(1))) unsigned int*)g,
        (__attribute__((address_space(3))) unsigned int*)l, 16, 0, 0);
}

// ---------------------------------------------------------------------------
// pack: fused repack of x -> xbf (bf16, 512B pixel rows, 16B granules
// XOR-swizzled by (pixel&7)<<4), conv weights -> wtb, proj weights -> wob.
// (unchanged)
// ---------------------------------------------------------------------------
__global__ __launch_bounds__(256) void pack_kernel(const float* __restrict__ x,
                                                   const float* __restrict__ ow,
                                                   const float* __restrict__ aw,
                                                   const float* __restrict__ wO,
                                                   unsigned int* __restrict__ xbf,
                                                   unsigned short* __restrict__ wtb,
                                                   unsigned short* __restrict__ wob) {
    int idx = blockIdx.x * 256 + threadIdx.x;
    if (idx < 262144) {
        int p = idx >> 5, g = idx & 31;
        const float4* src = reinterpret_cast<const float4*>(x + ((size_t)p * 256 + g * 8));
        float4 lo = src[0], hi = src[1];
        uint4 o;
        o.x = f2bf(lo.x) | ((unsigned)f2bf(lo.y) << 16);
        o.y = f2bf(lo.z) | ((unsigned)f2bf(lo.w) << 16);
        o.z = f2bf(hi.x) | ((unsigned)f2bf(hi.y) << 16);
        o.w = f2bf(hi.z) | ((unsigned)f2bf(hi.w) << 16);
        int byte = (g * 16) ^ ((p & 7) << 4);
        *reinterpret_cast<uint4*>((char*)xbf + (size_t)p * 512 + byte) = o;
    } else if (idx < 483328) {
        int o = idx - 262144;              // (tap*96+ch)*256 + ci
        int ci = o & 255; int t = o >> 8; int ch = t % 96; int tap = t / 96;
        float v = (ch < 64) ? ow[((size_t)ch * 256 + ci) * 9 + tap]
                            : aw[((size_t)(ch - 64) * 256 + ci) * 9 + tap];
        size_t base = (size_t)(tap * 96 + ch) * 512;
        int byte = (2 * ci) ^ ((ch & 7) << 4);
        *reinterpret_cast<unsigned short*>((char*)wtb + base + byte) = f2bf(v);
    } else {
        int o = idx - 483328;              // n*256 + k
        int k = o & 255, n = o >> 8;
        int byte = (2 * k) ^ ((n & 7) << 4);
        *reinterpret_cast<unsigned short*>((char*)wob + (size_t)n * 512 + byte) = f2bf(wO[o]);
    }
}

// ---------------------------------------------------------------------------
// conv v5: implicit-GEMM 3x3 SAME conv; schedule identical to v4 (proven).
// ONLY change: output layout is now channels-LAST: conv2[b*4096+pix][128]
// (96 channels used, 32 pad) so sample's coef reads coalesce.
// ---------------------------------------------------------------------------
__global__ __launch_bounds__(256, 2) void conv_kernel(const unsigned int* __restrict__ xbf,
                                                      const unsigned short* __restrict__ wtb,
                                                      const float* __restrict__ offb,
                                                      const float* __restrict__ attb,
                                                      float* __restrict__ conv) {
    __shared__ char lds[66560];            // A: 17408 B, B: 2 x 24576 B
    char* ldsA = lds;
    char* ldsB0 = lds + 17408;
    char* ldsB1 = lds + 17408 + 24576;
    int blk = blockIdx.x;
    int xh = blk & 1, y = (blk >> 1) & 63, b = (blk >> 7) & 1, chh = (blk >> 8) & 1;
    int x0 = xh * 32, ch0 = chh * 48;
    int tid = threadIdx.x, wid = tid >> 6, lane = tid & 63;
    int l15 = lane & 15, l7 = lane & 7, hi16 = (lane >> 4) * 16;

    f32x4 acc[2][3];
#pragma unroll
    for (int mf = 0; mf < 2; ++mf)
#pragma unroll
        for (int nf = 0; nf < 3; ++nf) acc[mf][nf] = (f32x4){0.f, 0.f, 0.f, 0.f};

#define STAGE_B(DST, TAP)                                                     \
    {                                                                         \
        const char* bsrc = (const char*)wtb + (size_t)((TAP) * 96 + ch0) * 512; \
        for (int i = 0; i < 6; ++i) {                                         \
            int g0 = i * 256 + wid * 64;                                      \
            gload_lds16(bsrc + (size_t)(g0 + lane) * 16, (DST) + g0 * 16);    \
        }                                                                     \
    }

    STAGE_B(ldsB0, 0);                     // prologue prefetch, in flight
    for (int ky = 0; ky < 3; ++ky) {
        int gy = y + ky - 1;
        __syncthreads();                   // prior tap's A reads done
        for (int g = tid; g < 1088; g += 256) {  // 34 px * 32 granules
            int px = g >> 5, go = g & 31;
            int gx = x0 - 1 + px;
            uint4 v = make_uint4(0, 0, 0, 0);
            if (gy >= 0 && gy < 64 && gx >= 0 && gx < 64) {
                size_t p = (size_t)b * 4096 + gy * 64 + gx;
                v = *reinterpret_cast<const uint4*>((const char*)xbf + p * 512 + go * 16);
            }
            *reinterpret_cast<uint4*>(ldsA + px * 512 + go * 16) = v;
        }
        for (int kx = 0; kx < 3; ++kx) {
            int tap = ky * 3 + kx;
            char* bcur = (tap & 1) ? ldsB1 : ldsB0;
            char* bnxt = (tap & 1) ? ldsB0 : ldsB1;
            __syncthreads();               // drains: B[tap] landed, A staged
            if (tap < 8) STAGE_B(bnxt, tap + 1);   // fly under this tap's MFMA
#pragma unroll
            for (int kk = 0; kk < 2; ++kk) {
                int key = ((l7 + kx + 7) & 7) << 4;   // (gx&7)<<4; x0 % 8 == 0
                int px0 = l15 + kx;
                bf16x8 a0 = *reinterpret_cast<const bf16x8*>(
                    ldsA + px0 * 512 + wid * 128 + ((kk * 64 + hi16) ^ key));
                bf16x8 a1 = *reinterpret_cast<const bf16x8*>(
                    ldsA + (px0 + 16) * 512 + wid * 128 + ((kk * 64 + hi16) ^ key));
#pragma unroll
                for (int nf = 0; nf < 3; ++nf) {
                    int ch = 16 * nf + l15;
                    bf16x8 bv = *reinterpret_cast<const bf16x8*>(
                        bcur + ch * 512 + wid * 128 + ((kk * 64 + hi16) ^ (l7 << 4)));
                    acc[0][nf] = __builtin_amdgcn_mfma_f32_16x16x32_bf16(a0, bv, acc[0][nf], 0, 0, 0);
                    acc[1][nf] = __builtin_amdgcn_mfma_f32_16x16x32_bf16(a1, bv, acc[1][nf], 0, 0, 0);
                }
            }
        }
    }
#undef STAGE_B
    // cross-wave K reduce: part[w][m 32][ch padded 52]
    __syncthreads();
    float* part = reinterpret_cast<float*>(lds);
#pragma unroll
    for (int mf = 0; mf < 2; ++mf)
#pragma unroll
        for (int nf = 0; nf < 3; ++nf)
#pragma unroll
            for (int r = 0; r < 4; ++r) {
                int m = 16 * mf + (lane >> 4) * 4 + r;
                int ch = 16 * nf + l15;
                part[(wid * 32 + m) * 52 + ch] = acc[mf][nf][r];
            }
    __syncthreads();
    int m = tid >> 3, c0 = (tid & 7) * 6;
    float* dst = conv + ((size_t)b * 4096 + y * 64 + x0 + m) * 128 + ch0 + c0;
#pragma unroll
    for (int j = 0; j < 6; ++j) {
        int ch = c0 + j;
        float v = part[m * 52 + ch] + part[(32 + m) * 52 + ch] +
                  part[(64 + m) * 52 + ch] + part[(96 + m) * 52 + ch];
        int chg = ch0 + ch;
        float bias = (chg < 64) ? offb[chg] : attb[chg - 64];
        dst[j] = v + bias;
    }
}

// ---------------------------------------------------------------------------
// sample v4: identical to v3 except conv is channels-last:
//   logit  = conv2[qp][64+s]   (one coalesced 128B segment per half-wave)
//   ox,oy  = conv2[qpT][2s],[2s+1] (256B contiguous)
// ---------------------------------------------------------------------------
__global__ __launch_bounds__(256) void sample_kernel(const unsigned int* __restrict__ xbf,
                                                     const float* __restrict__ conv,
                                                     unsigned int* __restrict__ S) {
    __shared__ float s_coef[4][32][4];
    __shared__ int s_pix[4][32][4];
    int tid = threadIdx.x, wid = tid >> 6, lane = tid & 63;
    int q = blockIdx.x * 4 + wid;
    int b = q >> 12, qi = (q >> 6) & 63, qj = q & 63;
    const float* convb = conv + (size_t)b * 4096 * 128;

    {
        int s = lane & 31, cp = lane >> 5;       // cp: corner pair {0,1},{2,3}
        int qp = qi * 64 + qj;                   // attn pixel
        int qpT = qj * 64 + qi;                  // offset pixel (transposed)
        float logit = convb[qp * 128 + 64 + s];
        float mx = logit;
        mx = fmaxf(mx, __shfl_xor(mx, 1));
        mx = fmaxf(mx, __shfl_xor(mx, 2));
        float e = __expf(logit - mx);
        float sum = e;
        sum += __shfl_xor(sum, 1);
        sum += __shfl_xor(sum, 2);
        float a = e / sum * 0.125f;

        float ox = convb[qpT * 128 + 2 * s];
        float oy = convb[qpT * 128 + 2 * s + 1];
        float gx = (float)qi * (1.f / 63.f) + 0.1f * ox;
        float gy = (float)qj * (1.f / 63.f) + 0.1f * oy;
        float ix = ((gx + 1.f) * 64.f - 1.f) * 0.5f;
        float iy = ((gy + 1.f) * 64.f - 1.f) * 0.5f;
        float x0f = floorf(ix), y0f = floorf(iy);
        float wx = ix - x0f, wy = iy - y0f;
        int x0 = (int)x0f, y0 = (int)y0f;
#pragma unroll
        for (int i = 0; i < 2; ++i) {
            int c = cp * 2 + i;
            int xi = x0 + (c & 1), yi = y0 + (c >> 1);
            float w = ((c & 1) ? wx : 1.f - wx) * ((c >> 1) ? wy : 1.f - wy);
            bool valid = (xi >= 0) && (xi < 64) && (yi >= 0) && (yi < 64);
            int xc = min(max(xi, 0), 63), yc = min(max(yi, 0), 63);
            int pix = yc * 64 + xc;
            s_coef[wid][s][c] = valid ? a * w : 0.f;
            s_pix[wid][s][c] = pix * 512 + ((pix & 7) << 4);  // pre-swizzled
        }
    }
    __syncthreads();

    const char* xb = (const char*)xbf + (size_t)b * 4096 * 512;
    int half = lane >> 5, l31 = lane & 31;
    int lbyte = l31 * 16;
    float acc[8] = {0.f, 0.f, 0.f, 0.f, 0.f, 0.f, 0.f, 0.f};
#pragma unroll 2
    for (int ss = 0; ss < 16; ++ss) {
        int s = ss * 2 + half;
        float4 cf = *reinterpret_cast<const float4*>(&s_coef[wid][s][0]);
        int4 pp = *reinterpret_cast<const int4*>(&s_pix[wid][s][0]);
        uint4 v0 = *reinterpret_cast<const uint4*>(xb + (unsigned)(pp.x ^ lbyte));
        uint4 v1 = *reinterpret_cast<const uint4*>(xb + (unsigned)(pp.y ^ lbyte));
        uint4 v2 = *reinterpret_cast<const uint4*>(xb + (unsigned)(pp.z ^ lbyte));
        uint4 v3 = *reinterpret_cast<const uint4*>(xb + (unsigned)(pp.w ^ lbyte));
#define FMA8(COEF, V)                                   \
        acc[0] = fmaf(COEF, bflo(V.x), acc[0]);         \
        acc[1] = fmaf(COEF, bfhi(V.x), acc[1]);         \
        acc[2] = fmaf(COEF, bflo(V.y), acc[2]);         \
        acc[3] = fmaf(COEF, bfhi(V.y), acc[3]);         \
        acc[4] = fmaf(COEF, bflo(V.z), acc[4]);         \
        acc[5] = fmaf(COEF, bfhi(V.z), acc[5]);         \
        acc[6] = fmaf(COEF, bflo(V.w), acc[6]);         \
        acc[7] = fmaf(COEF, bfhi(V.w), acc[7]);
        FMA8(cf.x, v0)
        FMA8(cf.y, v1)
        FMA8(cf.z, v2)
        FMA8(cf.w, v3)
#undef FMA8
    }
#pragma unroll
    for (int i = 0; i < 8; ++i) acc[i] += __shfl_xor(acc[i], 32);
    if (lane < 32) {
        uint4 o;
        o.x = f2bf(acc[0]) | ((unsigned)f2bf(acc[1]) << 16);
        o.y = f2bf(acc[2]) | ((unsigned)f2bf(acc[3]) << 16);
        o.z = f2bf(acc[4]) | ((unsigned)f2bf(acc[5]) << 16);
        o.w = f2bf(acc[6]) | ((unsigned)f2bf(acc[7]) << 16);
        *reinterpret_cast<uint4*>((char*)S + (size_t)q * 512 +
                                  (lbyte ^ ((q & 7) << 4))) = o;
    }
}

// ---------------------------------------------------------------------------
// gemm: out[m][n] = S[m][k] . wob[n][k] + b[n].  M=8192 N=256 K=256.
// (unchanged — proven)
// ---------------------------------------------------------------------------
__global__ __launch_bounds__(256, 2) void gemm_kernel(const char* __restrict__ S,
                                                      const char* __restrict__ wob,
                                                      const float* __restrict__ bO,
                                                      float* __restrict__ out) {
    __shared__ char lds[65536];
    char* ldsA = lds;
    char* ldsB = lds + 32768;
    int bm = blockIdx.x, bn = blockIdx.y;
    int tid = threadIdx.x, wid = tid >> 6, lane = tid & 63;
    int wm = wid >> 1, wn = wid & 1;
    int l15 = lane & 15, l7 = lane & 7, hi16 = (lane >> 4) * 16;
    const char* srcA = S + (size_t)bm * 64 * 512;
    const char* srcB = wob + (size_t)bn * 64 * 512;
    for (int i = 0; i < 8; ++i) {
        int g0 = i * 256 + wid * 64;
        gload_lds16(srcA + (size_t)(g0 + lane) * 16, ldsA + g0 * 16);
        gload_lds16(srcB + (size_t)(g0 + lane) * 16, ldsB + g0 * 16);
    }
    f32x4 acc[2][2];
#pragma unroll
    for (int mf = 0; mf < 2; ++mf)
#pragma unroll
        for (int nf = 0; nf < 2; ++nf) acc[mf][nf] = (f32x4){0.f, 0.f, 0.f, 0.f};
    __syncthreads();
#pragma unroll
    for (int kk = 0; kk < 8; ++kk) {
        bf16x8 a[2], bv[2];
#pragma unroll
        for (int mf = 0; mf < 2; ++mf) {
            int row = 32 * wm + 16 * mf + l15;
            a[mf] = *reinterpret_cast<const bf16x8*>(
                ldsA + row * 512 + ((kk * 64 + hi16) ^ (l7 << 4)));
        }
#pragma unroll
        for (int nf = 0; nf < 2; ++nf) {
            int row = 32 * wn + 16 * nf + l15;
            bv[nf] = *reinterpret_cast<const bf16x8*>(
                ldsB + row * 512 + ((kk * 64 + hi16) ^ (l7 << 4)));
        }
#pragma unroll
        for (int mf = 0; mf < 2; ++mf)
#pragma unroll
            for (int nf = 0; nf < 2; ++nf)
                acc[mf][nf] = __builtin_amdgcn_mfma_f32_16x16x32_bf16(a[mf], bv[nf], acc[mf][nf], 0, 0, 0);
    }
#pragma unroll
    for (int mf = 0; mf < 2; ++mf)
#pragma unroll
        for (int nf = 0; nf < 2; ++nf) {
            int n = bn * 64 + 32 * wn + 16 * nf + l15;
            float bias = bO[n];
#pragma unroll
            for (int r = 0; r < 4; ++r) {
                int m = bm * 64 + 32 * wm + 16 * mf + (lane >> 4) * 4 + r;
                out[(size_t)m * 256 + n] = acc[mf][nf][r] + bias;
            }
        }
}

extern "C" void kernel_launch(void* const* d_in, const int* in_sizes, int n_in,
                              void* d_out, int out_size, void* d_ws, size_t ws_size,
                              hipStream_t stream) {
    const float* x  = (const float*)d_in[0];
    const float* ow = (const float*)d_in[1];
    const float* ob = (const float*)d_in[2];
    const float* aw = (const float*)d_in[3];
    const float* ab = (const float*)d_in[4];
    const float* wO = (const float*)d_in[5];
    const float* bO = (const float*)d_in[6];
    float* out = (float*)d_out;

    char* ws = (char*)d_ws;
    unsigned int*   xbf = (unsigned int*)(ws);                 // 4,194,304 B
    unsigned short* wtb = (unsigned short*)(ws + 4194304);     //   442,368 B
    unsigned short* wob = (unsigned short*)(ws + 4636672);     //   131,072 B
    float*          cnv = (float*)(ws + 4767744);              // 4,194,304 B (ch-last, 128/pix)
    unsigned int*   S   = (unsigned int*)(ws + 8962048);       // 4,194,304 B

    hipLaunchKernelGGL(pack_kernel, dim3(2144), dim3(256), 0, stream,
                       x, ow, aw, wO, xbf, wtb, wob);
    hipLaunchKernelGGL(conv_kernel, dim3(512), dim3(256), 0, stream,
                       xbf, wtb, ob, ab, cnv);
    hipLaunchKernelGGL(sample_kernel, dim3(2048), dim3(256), 0, stream, xbf, cnv, S);
    hipLaunchKernelGGL(gemm_kernel, dim3(128, 4), dim3(256), 0, stream,
                       (const char*)S, (const char*)wob, bO, out);
}